// Round 1
// baseline (588.447 us; speedup 1.0000x reference)
//
#include <hip/hip_runtime.h>

typedef unsigned short u16;
typedef __attribute__((ext_vector_type(8))) short bf16x8;
typedef __attribute__((ext_vector_type(4))) float f32x4;

#define BATCH 4
#define SEQ   2048
#define DM    1024
#define HEADS 16
#define FEAT  16
#define HD    64
#define EXPD  273
#define EXPP  288   // padded to multiple of 32 for MFMA K
#define CHK   64
#define NC    32    // SEQ / CHK
#define BH    64    // BATCH*HEADS
#define C2    0.17677669529663687f  // 1/(sqrt(2)*sqrt(16))

__device__ __forceinline__ u16 f2b(float f) {
  union { float f; unsigned u; } v; v.f = f;
  unsigned u = v.u;
  return (u16)((u + 0x7fffu + ((u >> 16) & 1u)) >> 16);
}
__device__ __forceinline__ float b2f(u16 s) {
  union { unsigned u; float f; } v; v.u = ((unsigned)s) << 16; return v.f;
}

__global__ __launch_bounds__(256) void castk(const float* __restrict__ in, u16* __restrict__ out, int n) {
  for (int i = blockIdx.x * blockDim.x + threadIdx.x; i < n; i += gridDim.x * blockDim.x)
    out[i] = f2b(in[i]);
}

// C = A(MxK bf16 rm) @ B(KxN bf16 rm) + bias; out fp32 or bf16. 64x64 tile, BK=32, 4 waves.
__global__ __launch_bounds__(256) void gemm64(const u16* __restrict__ A, const u16* __restrict__ Bm,
                                              const float* __restrict__ bias, int M, int N, int K,
                                              float* __restrict__ outF, u16* __restrict__ outB) {
  __shared__ u16 Al[64][40];
  __shared__ u16 Bt[64][40];  // transposed: [n][k]
  const int tid = threadIdx.x;
  const int wave = tid >> 6, lane = tid & 63, qd = lane >> 4, ln = lane & 15;
  const int n0 = blockIdx.x * 64, m0 = blockIdx.y * 64;
  f32x4 acc[4];
  for (int nt = 0; nt < 4; nt++) acc[nt] = (f32x4){0.f, 0.f, 0.f, 0.f};
  const int ar = tid >> 2, ac = (tid & 3) * 8;
  const int br = tid >> 3, bc = (tid & 7) * 8;
  for (int kk = 0; kk < K; kk += 32) {
    uint4 av = *(const uint4*)&A[(size_t)(m0 + ar) * K + kk + ac];
    uint4 bv = *(const uint4*)&Bm[(size_t)(kk + br) * N + n0 + bc];
    *(uint4*)&Al[ar][ac] = av;
    union { uint4 v; u16 s[8]; } bu; bu.v = bv;
#pragma unroll
    for (int j = 0; j < 8; j++) Bt[bc + j][br] = bu.s[j];
    __syncthreads();
    bf16x8 a = *(const bf16x8*)&Al[wave * 16 + ln][qd * 8];
#pragma unroll
    for (int nt = 0; nt < 4; nt++) {
      bf16x8 b = *(const bf16x8*)&Bt[nt * 16 + ln][qd * 8];
      acc[nt] = __builtin_amdgcn_mfma_f32_16x16x32_bf16(a, b, acc[nt], 0, 0, 0);
    }
    __syncthreads();
  }
#pragma unroll
  for (int nt = 0; nt < 4; nt++) {
    int col = n0 + nt * 16 + ln;
    float bias_v = bias[col];
#pragma unroll
    for (int r = 0; r < 4; r++) {
      int row = m0 + wave * 16 + qd * 4 + r;
      float v = acc[nt][r] + bias_v;
      if (outF) outF[(size_t)row * N + col] = v;
      else      outB[(size_t)row * N + col] = f2b(v);
    }
  }
}

// Per (b,h,chunk): ckv[e][hd] = sum_t Kf[t][e]*V[t][hd]  (bf16), ck[e] = colsum Kf (fp32)
__global__ __launch_bounds__(256) void chunk_sums(const float* __restrict__ kq, const u16* __restrict__ vb,
                                                  u16* __restrict__ ckv, float* __restrict__ ck) {
  __shared__ float kl[64][16];
  __shared__ u16 vl[64][72];
  __shared__ u16 kf[64][17];
  const int tid = threadIdx.x;
  const int bh = blockIdx.x / NC, c = blockIdx.x % NC;
  const int b = bh >> 4, h = bh & 15;
  const int wave = tid >> 6, lane = tid & 63, qd = lane >> 4, ln = lane & 15;
  const size_t rowbase = (size_t)(b * SEQ + c * CHK);
  for (int i = tid; i < 64 * 16; i += 256) {
    int tt = i >> 4, f = i & 15;
    kl[tt][f] = kq[(rowbase + tt) * (HEADS * FEAT) + h * FEAT + f];
  }
  for (int i = tid; i < 512; i += 256) {
    int tt = i >> 3, db = (i & 7) * 8;
    *(uint4*)&vl[tt][db] = *(const uint4*)&vb[(rowbase + tt) * DM + h * HD + db];
  }
  __syncthreads();
  const size_t obase = (size_t)(bh * NC + c) * EXPP * HD;
  for (int mt = 0; mt < 18; mt++) {
    for (int i = tid; i < 64 * 16; i += 256) {
      int tt = i >> 4, el = i & 15;
      int e = mt * 16 + el;
      float val;
      if (e == 0) val = 1.0f;
      else if (e < 17) val = 0.5f * kl[tt][e - 1];
      else if (e < EXPD) { int u = e - 17; val = C2 * kl[tt][u >> 4] * kl[tt][u & 15]; }
      else val = 0.0f;
      kf[tt][el] = f2b(val);
    }
    __syncthreads();
    f32x4 acc = (f32x4){0.f, 0.f, 0.f, 0.f};
#pragma unroll
    for (int kk = 0; kk < 64; kk += 32) {
      bf16x8 a, bb;
#pragma unroll
      for (int j = 0; j < 8; j++) {
        int tt = kk + qd * 8 + j;
        a[j]  = (short)kf[tt][ln];
        bb[j] = (short)vl[tt][wave * 16 + ln];
      }
      acc = __builtin_amdgcn_mfma_f32_16x16x32_bf16(a, bb, acc, 0, 0, 0);
    }
#pragma unroll
    for (int r = 0; r < 4; r++) {
      int e = mt * 16 + qd * 4 + r;
      int hd = wave * 16 + ln;
      ckv[obase + (size_t)e * HD + hd] = f2b(acc[r]);
    }
    __syncthreads();
  }
  for (int e = tid; e < EXPP; e += 256) {
    float s = 0.f;
    if (e == 0) s = 64.f;
    else if (e < 17) { float t = 0.f; for (int tt = 0; tt < 64; tt++) t += kl[tt][e - 1]; s = 0.5f * t; }
    else if (e < EXPD) {
      int u = e - 17, i0 = u >> 4, j0 = u & 15; float t = 0.f;
      for (int tt = 0; tt < 64; tt++) t += kl[tt][i0] * kl[tt][j0];
      s = C2 * t;
    }
    ck[(size_t)(bh * NC + c) * EXPP + e] = s;
  }
}

// Exclusive prefix over chunks (in place, bf16); final inclusive state (+input kv_state) -> d_out
__global__ __launch_bounds__(256) void kv_prefix(u16* __restrict__ ckv, const float* __restrict__ kv0,
                                                 float* __restrict__ out_kv) {
  const int tid = threadIdx.x;
  const int bh = blockIdx.x >> 2, g = blockIdx.x & 3;
  const int hd = g * 16 + (tid & 15);
  const int er = tid >> 4;  // 0..15
  float S[18];
#pragma unroll
  for (int rr = 0; rr < 18; rr++) {
    int e = er + 16 * rr;
    S[rr] = (e < EXPD) ? kv0[((size_t)bh * EXPD + e) * HD + hd] : 0.f;
  }
  for (int c = 0; c < NC; c++) {
    size_t base = (size_t)(bh * NC + c) * EXPP * HD;
#pragma unroll
    for (int rr = 0; rr < 18; rr++) {
      int e = er + 16 * rr;
      size_t idx = base + (size_t)e * HD + hd;
      float v = b2f(ckv[idx]);
      ckv[idx] = f2b(S[rr]);
      S[rr] += v;
    }
  }
#pragma unroll
  for (int rr = 0; rr < 18; rr++) {
    int e = er + 16 * rr;
    if (e < EXPD) out_kv[((size_t)bh * EXPD + e) * HD + hd] = S[rr];
  }
}

__global__ __launch_bounds__(256) void kst_prefix(float* __restrict__ ck, const float* __restrict__ k0,
                                                  float* __restrict__ out_k) {
  const int bh = blockIdx.x;
  for (int e = threadIdx.x; e < EXPP; e += 256) {
    float S = (e < EXPD) ? k0[(size_t)bh * EXPD + e] : 0.f;
    for (int c = 0; c < NC; c++) {
      size_t idx = (size_t)(bh * NC + c) * EXPP + e;
      float v = ck[idx];
      ck[idx] = S;
      S += v;
    }
    if (e < EXPD) out_k[(size_t)bh * EXPD + e] = S;
  }
}

// Per (b,h,chunk): O = (Qf@S + mask(Qf Kf^T)@V) / den  -> o (bf16, (B*L, H*HD))
__global__ __launch_bounds__(256) void out_chunk(const float* __restrict__ qq, const float* __restrict__ kq,
                                                 const u16* __restrict__ vb, const u16* __restrict__ ckv,
                                                 const float* __restrict__ ck, u16* __restrict__ ob) {
  __shared__ float ql[64][16];
  __shared__ float kl[64][16];
  __shared__ u16 vl[64][72];
  __shared__ u16 qf[64][40];
  __shared__ u16 kf[64][40];
  __shared__ u16 st[32][72];
  __shared__ u16 al[64][72];
  __shared__ float denl[64];
  __shared__ float kstl[EXPP];
  const int tid = threadIdx.x;
  const int bh = blockIdx.x / NC, c = blockIdx.x % NC;
  const int b = bh >> 4, h = bh & 15;
  const int wave = tid >> 6, lane = tid & 63, qd = lane >> 4, ln = lane & 15;
  const size_t rowbase = (size_t)(b * SEQ + c * CHK);
  for (int i = tid; i < 64 * 16; i += 256) {
    int tt = i >> 4, f = i & 15;
    ql[tt][f] = qq[(rowbase + tt) * (HEADS * FEAT) + h * FEAT + f];
    kl[tt][f] = kq[(rowbase + tt) * (HEADS * FEAT) + h * FEAT + f];
  }
  for (int i = tid; i < 512; i += 256) {
    int tt = i >> 3, db = (i & 7) * 8;
    *(uint4*)&vl[tt][db] = *(const uint4*)&vb[(rowbase + tt) * DM + h * HD + db];
  }
  const size_t cbase = (size_t)(bh * NC + c);
  for (int e = tid; e < EXPP; e += 256) kstl[e] = ck[cbase * EXPP + e];
  __syncthreads();
  f32x4 accA[4], accO[4];
  for (int mt = 0; mt < 4; mt++) { accA[mt] = (f32x4){0,0,0,0}; accO[mt] = (f32x4){0,0,0,0}; }
  const size_t sbase = cbase * EXPP * HD;
  for (int kt = 0; kt < 9; kt++) {
    for (int i = tid; i < 2048; i += 256) {
      int tt = i >> 5, el = i & 31;
      int e = kt * 32 + el;
      float qv, kv;
      if (e == 0) { qv = 1.f; kv = 1.f; }
      else if (e < 17) { qv = 0.5f * ql[tt][e - 1]; kv = 0.5f * kl[tt][e - 1]; }
      else if (e < EXPD) {
        int u = e - 17, i0 = u >> 4, j0 = u & 15;
        qv = C2 * ql[tt][i0] * ql[tt][j0];
        kv = C2 * kl[tt][i0] * kl[tt][j0];
      } else { qv = 0.f; kv = 0.f; }
      qf[tt][el] = f2b(qv); kf[tt][el] = f2b(kv);
    }
    {
      int kr = tid >> 3, db = (tid & 7) * 8;
      *(uint4*)&st[kr][db] = *(const uint4*)&ckv[sbase + (size_t)(kt * 32 + kr) * HD + db];
    }
    __syncthreads();
    bf16x8 bA = *(const bf16x8*)&kf[wave * 16 + ln][qd * 8];
    bf16x8 bO;
#pragma unroll
    for (int j = 0; j < 8; j++) bO[j] = (short)st[qd * 8 + j][wave * 16 + ln];
#pragma unroll
    for (int mt = 0; mt < 4; mt++) {
      bf16x8 a = *(const bf16x8*)&qf[mt * 16 + ln][qd * 8];
      accA[mt] = __builtin_amdgcn_mfma_f32_16x16x32_bf16(a, bA, accA[mt], 0, 0, 0);
      accO[mt] = __builtin_amdgcn_mfma_f32_16x16x32_bf16(a, bO, accO[mt], 0, 0, 0);
    }
    __syncthreads();
  }
#pragma unroll
  for (int mt = 0; mt < 4; mt++) {
#pragma unroll
    for (int r = 0; r < 4; r++) {
      int t = mt * 16 + qd * 4 + r;
      int s = wave * 16 + ln;
      al[t][s] = f2b((s <= t) ? accA[mt][r] : 0.f);
    }
  }
  __syncthreads();
  if (tid < 64) {
    int t = tid;
    float da = 0.f;
    for (int s = 0; s < 64; s++) da += b2f(al[t][s]);
    float qv[16];
#pragma unroll
    for (int i = 0; i < 16; i++) qv[i] = ql[t][i];
    float di = kstl[0];
    float s1 = 0.f;
#pragma unroll
    for (int i = 0; i < 16; i++) s1 += qv[i] * kstl[1 + i];
    di += 0.5f * s1;
    float s2 = 0.f;
    for (int i = 0; i < 16; i++) {
      float inner = 0.f;
#pragma unroll
      for (int j = 0; j < 16; j++) inner += qv[j] * kstl[17 + i * 16 + j];
      s2 += qv[i] * inner;
    }
    di += C2 * s2;
    denl[t] = da + di + 1e-6f;
  }
  __syncthreads();
#pragma unroll
  for (int kk = 0; kk < 64; kk += 32) {
    bf16x8 bb;
#pragma unroll
    for (int j = 0; j < 8; j++) bb[j] = (short)vl[kk + qd * 8 + j][wave * 16 + ln];
#pragma unroll
    for (int mt = 0; mt < 4; mt++) {
      bf16x8 a = *(const bf16x8*)&al[mt * 16 + ln][kk + qd * 8];
      accO[mt] = __builtin_amdgcn_mfma_f32_16x16x32_bf16(a, bb, accO[mt], 0, 0, 0);
    }
  }
#pragma unroll
  for (int mt = 0; mt < 4; mt++) {
#pragma unroll
    for (int r = 0; r < 4; r++) {
      int t = mt * 16 + qd * 4 + r;
      int hd = wave * 16 + ln;
      ob[(rowbase + t) * DM + h * HD + hd] = f2b(accO[mt][r] / denl[t]);
    }
  }
}

extern "C" void kernel_launch(void* const* d_in, const int* in_sizes, int n_in,
                              void* d_out, int out_size, void* d_ws, size_t ws_size,
                              hipStream_t stream) {
  (void)in_sizes; (void)n_in; (void)out_size;
  const float* x   = (const float*)d_in[0];
  const float* kv0 = (const float*)d_in[1];
  const float* k0  = (const float*)d_in[2];
  const float* bq  = (const float*)d_in[4];
  const float* bk  = (const float*)d_in[6];
  const float* bv  = (const float*)d_in[8];
  const float* bo  = (const float*)d_in[10];
  float* out = (float*)d_out;
  char* ws = (char*)d_ws;
  size_t off = 0;
  auto take = [&](size_t bytes) { char* p = ws + off; off += (bytes + 255) & ~(size_t)255; return p; };
  u16*   xb  = (u16*)  take((size_t)BATCH * SEQ * DM * 2);
  u16*   wqb = (u16*)  take((size_t)DM * 256 * 2);
  u16*   wkb = (u16*)  take((size_t)DM * 256 * 2);
  u16*   wvb = (u16*)  take((size_t)DM * DM * 2);
  u16*   wob = (u16*)  take((size_t)DM * DM * 2);
  float* qw  = (float*)take((size_t)BATCH * SEQ * 256 * 4);
  float* kw  = (float*)take((size_t)BATCH * SEQ * 256 * 4);
  u16*   vb  = (u16*)  take((size_t)BATCH * SEQ * DM * 2);
  u16*   ckv = (u16*)  take((size_t)BH * NC * EXPP * HD * 2);
  float* ck  = (float*)take((size_t)BH * NC * EXPP * 4);
  u16*   ob  = (u16*)  take((size_t)BATCH * SEQ * DM * 2);
  if (off > ws_size) return;  // workspace too small: fail loudly (no OOB writes)

  castk<<<1024, 256, 0, stream>>>(x, xb, BATCH * SEQ * DM);
  castk<<<256, 256, 0, stream>>>((const float*)d_in[3], wqb, DM * 256);
  castk<<<256, 256, 0, stream>>>((const float*)d_in[5], wkb, DM * 256);
  castk<<<1024, 256, 0, stream>>>((const float*)d_in[7], wvb, DM * DM);
  castk<<<1024, 256, 0, stream>>>((const float*)d_in[9], wob, DM * DM);

  gemm64<<<dim3(4, 128), 256, 0, stream>>>(xb, wqb, bq, BATCH * SEQ, 256, DM, qw, nullptr);
  gemm64<<<dim3(4, 128), 256, 0, stream>>>(xb, wkb, bk, BATCH * SEQ, 256, DM, kw, nullptr);
  gemm64<<<dim3(16, 128), 256, 0, stream>>>(xb, wvb, bv, BATCH * SEQ, DM, DM, nullptr, vb);

  chunk_sums<<<BH * NC, 256, 0, stream>>>(kw, vb, ckv, ck);
  kv_prefix<<<BH * 4, 256, 0, stream>>>(ckv, kv0, out + (size_t)BATCH * SEQ * DM);
  kst_prefix<<<BH, 256, 0, stream>>>(ck, k0, out + (size_t)BATCH * SEQ * DM + (size_t)BH * EXPD * HD);
  out_chunk<<<BH * NC, 256, 0, stream>>>(qw, kw, vb, ckv, ck, ob);

  gemm64<<<dim3(16, 128), 256, 0, stream>>>(ob, wob, bo, BATCH * SEQ, DM, DM, out, nullptr);
}

// Round 2
// 400.270 us; speedup vs baseline: 1.4701x; 1.4701x over previous
//
#include <hip/hip_runtime.h>

typedef unsigned short u16;
typedef __attribute__((ext_vector_type(8))) short bf16x8;
typedef __attribute__((ext_vector_type(4))) float f32x4;

#define BATCH 4
#define SEQ   2048
#define DM    1024
#define HEADS 16
#define FEAT  16
#define HD    64
#define EXPD  273
#define EXPP  288   // padded to multiple of 32 for MFMA K
#define CHK   64
#define NC    32    // SEQ / CHK
#define BH    64    // BATCH*HEADS
#define QKS   512   // fused QK projection row stride
#define C2    0.17677669529663687f  // 1/(sqrt(2)*sqrt(16))

__device__ __forceinline__ u16 f2b(float f) {
  union { float f; unsigned u; } v; v.f = f;
  unsigned u = v.u;
  return (u16)((u + 0x7fffu + ((u >> 16) & 1u)) >> 16);
}
__device__ __forceinline__ float b2f(u16 s) {
  union { unsigned u; float f; } v; v.u = ((unsigned)s) << 16; return v.f;
}

typedef const unsigned int __attribute__((address_space(1)))* gas1;
typedef unsigned int __attribute__((address_space(3)))* las3;
__device__ __forceinline__ void gl_lds16(const u16* g, u16* l) {
  __builtin_amdgcn_global_load_lds((gas1)(const void*)g, (las3)(void*)l, 16, 0, 0);
}

__global__ __launch_bounds__(256) void castk(const float* __restrict__ in, u16* __restrict__ out, int n4) {
  int i = blockIdx.x * 256 + threadIdx.x;
  if (i < n4) {
    float4 v = ((const float4*)in)[i];
    u16 r[4] = {f2b(v.x), f2b(v.y), f2b(v.z), f2b(v.w)};
    ((uint2*)out)[i] = *(uint2*)r;
  }
}

// in: [K][N] fp32 row-major -> out: [N][K] bf16 row-major
__global__ __launch_bounds__(256) void castT(const float* __restrict__ in, u16* __restrict__ out, int K, int N) {
  __shared__ float tile[32][33];
  int n0 = blockIdx.x * 32, k0 = blockIdx.y * 32;
  int tx = threadIdx.x & 31, ty = threadIdx.x >> 5;
  for (int i = ty; i < 32; i += 8)
    tile[i][tx] = in[(size_t)(k0 + i) * N + n0 + tx];
  __syncthreads();
  for (int i = ty; i < 32; i += 8)
    out[(size_t)(n0 + i) * K + k0 + tx] = f2b(tile[tx][i]);
}

__global__ __launch_bounds__(256) void concatb(const float* __restrict__ a, const float* __restrict__ b,
                                               float* __restrict__ o) {
  int i = blockIdx.x * 256 + threadIdx.x;
  if (i < 256) o[i] = a[i];
  else if (i < 512) o[i] = b[i - 256];
}

// C = A(MxK bf16 rm) @ BT^T + bias.  BT is [N][K] bf16 row-major.
// 128x128 tile, BK=32, 4 waves (2x2), global_load_lds staging (m97 structure).
__global__ __launch_bounds__(256) void gemm128(const u16* __restrict__ A, const u16* __restrict__ BT,
                                               const float* __restrict__ bias, int M, int N, int K,
                                               float* __restrict__ outF, u16* __restrict__ outB) {
  __shared__ __align__(16) u16 As[128 * 32];
  __shared__ __align__(16) u16 Bs[128 * 32];
  const int tid = threadIdx.x;
  const int wave = tid >> 6, lane = tid & 63, qd = lane >> 4, ln = lane & 15;
  const int wr = (wave >> 1) * 64, wc = (wave & 1) * 64;
  const int m0 = blockIdx.y * 128, n0 = blockIdx.x * 128;
  f32x4 acc[4][4];
#pragma unroll
  for (int i = 0; i < 4; i++)
#pragma unroll
    for (int j = 0; j < 4; j++) acc[i][j] = (f32x4){0.f, 0.f, 0.f, 0.f};
  const int sr = tid >> 2, sk = (tid & 3) * 8;
  const u16* gA0 = A + (size_t)(m0 + sr) * K + sk;
  const u16* gA1 = A + (size_t)(m0 + 64 + sr) * K + sk;
  const u16* gB0 = BT + (size_t)(n0 + sr) * K + sk;
  const u16* gB1 = BT + (size_t)(n0 + 64 + sr) * K + sk;
  u16* lA0 = &As[(size_t)(wave * 64) * 8];
  u16* lA1 = &As[(size_t)(256 + wave * 64) * 8];
  u16* lB0 = &Bs[(size_t)(wave * 64) * 8];
  u16* lB1 = &Bs[(size_t)(256 + wave * 64) * 8];
  for (int kk = 0; kk < K; kk += 32) {
    gl_lds16(gA0 + kk, lA0);
    gl_lds16(gA1 + kk, lA1);
    gl_lds16(gB0 + kk, lB0);
    gl_lds16(gB1 + kk, lB1);
    __syncthreads();
    bf16x8 af[4], bf[4];
#pragma unroll
    for (int t = 0; t < 4; t++) {
      af[t] = *(const bf16x8*)&As[(wr + t * 16 + ln) * 32 + qd * 8];
      bf[t] = *(const bf16x8*)&Bs[(wc + t * 16 + ln) * 32 + qd * 8];
    }
#pragma unroll
    for (int mt = 0; mt < 4; mt++)
#pragma unroll
      for (int nt = 0; nt < 4; nt++)
        acc[mt][nt] = __builtin_amdgcn_mfma_f32_16x16x32_bf16(af[mt], bf[nt], acc[mt][nt], 0, 0, 0);
    __syncthreads();
  }
#pragma unroll
  for (int nt = 0; nt < 4; nt++) {
    int col = n0 + wc + nt * 16 + ln;
    float bv = bias[col];
#pragma unroll
    for (int mt = 0; mt < 4; mt++) {
#pragma unroll
      for (int r = 0; r < 4; r++) {
        int row = m0 + wr + mt * 16 + qd * 4 + r;
        float v = acc[mt][nt][r] + bv;
        if (outF) outF[(size_t)row * N + col] = v;
        else      outB[(size_t)row * N + col] = f2b(v);
      }
    }
  }
}

// Per (b,h,chunk): ckv[e][hd] = sum_t Kf[t][e]*V[t][hd] (bf16), ck[e] = colsum Kf (fp32)
// Waves own e-tiles (private kfT buffers) -> single barrier per block.
__global__ __launch_bounds__(256) void chunk_sums(const float* __restrict__ qkw, const u16* __restrict__ vb,
                                                  u16* __restrict__ ckv, float* __restrict__ ck) {
  __shared__ float kl[64][17];
  __shared__ u16 vlT[64][72];    // [hd][t]
  __shared__ __align__(16) u16 kfT[4][16][72];  // per-wave [e_local][t]
  const int tid = threadIdx.x;
  const int bh = blockIdx.x / NC, c = blockIdx.x % NC;
  const int b = bh >> 4, h = bh & 15;
  const int wave = tid >> 6, lane = tid & 63, qd = lane >> 4, ln = lane & 15;
  const size_t rowbase = (size_t)(b * SEQ + c * CHK);
  {
    int tt = tid >> 2, f0 = (tid & 3) * 4;
    float4 v = *(const float4*)&qkw[(rowbase + tt) * QKS + 256 + h * FEAT + f0];
    kl[tt][f0] = v.x; kl[tt][f0 + 1] = v.y; kl[tt][f0 + 2] = v.z; kl[tt][f0 + 3] = v.w;
  }
  for (int i = tid; i < 512; i += 256) {
    int tt = i >> 3, db = (i & 7) * 8;
    union { uint4 v; u16 s[8]; } u;
    u.v = *(const uint4*)&vb[(rowbase + tt) * DM + h * HD + db];
#pragma unroll
    for (int j = 0; j < 8; j++) vlT[db + j][tt] = u.s[j];
  }
  __syncthreads();
  const size_t obase = (size_t)(bh * NC + c) * EXPP * HD;
  for (int mt = wave; mt < 18; mt += 4) {
#pragma unroll
    for (int el = 0; el < 16; el++) {
      int e = mt * 16 + el;
      float val;
      if (e == 0) val = 1.0f;
      else if (e < 17) val = 0.5f * kl[lane][e - 1];
      else if (e < EXPD) { int u = e - 17; val = C2 * kl[lane][u >> 4] * kl[lane][u & 15]; }
      else val = 0.0f;
      kfT[wave][el][lane] = f2b(val);
    }
    f32x4 acc[4];
#pragma unroll
    for (int nt = 0; nt < 4; nt++) acc[nt] = (f32x4){0.f, 0.f, 0.f, 0.f};
#pragma unroll
    for (int kk = 0; kk < 64; kk += 32) {
      bf16x8 a = *(const bf16x8*)&kfT[wave][ln][kk + qd * 8];
#pragma unroll
      for (int nt = 0; nt < 4; nt++) {
        bf16x8 bb = *(const bf16x8*)&vlT[nt * 16 + ln][kk + qd * 8];
        acc[nt] = __builtin_amdgcn_mfma_f32_16x16x32_bf16(a, bb, acc[nt], 0, 0, 0);
      }
    }
#pragma unroll
    for (int nt = 0; nt < 4; nt++)
#pragma unroll
      for (int r = 0; r < 4; r++) {
        int e = mt * 16 + qd * 4 + r;
        ckv[obase + (size_t)e * HD + nt * 16 + ln] = f2b(acc[nt][r]);
      }
  }
  for (int e = tid; e < EXPP; e += 256) {
    float s = 0.f;
    if (e == 0) s = 64.f;
    else if (e < 17) { float t = 0.f; for (int tt = 0; tt < 64; tt++) t += kl[tt][e - 1]; s = 0.5f * t; }
    else if (e < EXPD) {
      int u = e - 17, i0 = u >> 4, j0 = u & 15; float t = 0.f;
      for (int tt = 0; tt < 64; tt++) t += kl[tt][i0] * kl[tt][j0];
      s = C2 * t;
    }
    ck[(size_t)(bh * NC + c) * EXPP + e] = s;
  }
}

// Exclusive prefix over chunks (in place, bf16); final inclusive state (+input kv_state) -> d_out
__global__ __launch_bounds__(256) void kv_prefix(u16* __restrict__ ckv, const float* __restrict__ kv0,
                                                 float* __restrict__ out_kv) {
  const int tid = threadIdx.x;
  const int bh = blockIdx.x >> 2, g = blockIdx.x & 3;
  const int hd = g * 16 + (tid & 15);
  const int er = tid >> 4;
  float S[18];
#pragma unroll
  for (int rr = 0; rr < 18; rr++) {
    int e = er + 16 * rr;
    S[rr] = (e < EXPD) ? kv0[((size_t)bh * EXPD + e) * HD + hd] : 0.f;
  }
  for (int c = 0; c < NC; c++) {
    size_t base = (size_t)(bh * NC + c) * EXPP * HD;
#pragma unroll
    for (int rr = 0; rr < 18; rr++) {
      int e = er + 16 * rr;
      size_t idx = base + (size_t)e * HD + hd;
      float v = b2f(ckv[idx]);
      ckv[idx] = f2b(S[rr]);
      S[rr] += v;
    }
  }
#pragma unroll
  for (int rr = 0; rr < 18; rr++) {
    int e = er + 16 * rr;
    if (e < EXPD) out_kv[((size_t)bh * EXPD + e) * HD + hd] = S[rr];
  }
}

__global__ __launch_bounds__(256) void kst_prefix(float* __restrict__ ck, const float* __restrict__ k0,
                                                  float* __restrict__ out_k) {
  const int bh = blockIdx.x;
  for (int e = threadIdx.x; e < EXPP; e += 256) {
    float S = (e < EXPD) ? k0[(size_t)bh * EXPD + e] : 0.f;
    for (int c = 0; c < NC; c++) {
      size_t idx = (size_t)(bh * NC + c) * EXPP + e;
      float v = ck[idx];
      ck[idx] = S;
      S += v;
    }
    if (e < EXPD) out_k[(size_t)bh * EXPD + e] = S;
  }
}

// Per (b,h,chunk): O = (Qf@S + mask_incl(Qf Kf^T)@V) / den
__global__ __launch_bounds__(256) void out_chunk(const float* __restrict__ qkw, const u16* __restrict__ vb,
                                                 const u16* __restrict__ ckv, const float* __restrict__ ck,
                                                 u16* __restrict__ ob) {
  __shared__ float ql[64][17];
  __shared__ float kl[64][17];
  __shared__ u16 vlT[64][72];                   // [hd][t]
  __shared__ __align__(16) char pool[10240];    // qf[64][40] + kf[64][40]; al[64][72] overlays
  __shared__ __align__(16) u16 stT[64][40];     // [hd][e_local]
  __shared__ float kstl[EXPP];
  __shared__ float denl[64];
  u16 (*qf)[40] = (u16(*)[40])pool;
  u16 (*kf)[40] = (u16(*)[40])(pool + 5120);
  u16 (*al)[72] = (u16(*)[72])pool;
  const int tid = threadIdx.x;
  const int bh = blockIdx.x / NC, c = blockIdx.x % NC;
  const int b = bh >> 4, h = bh & 15;
  const int wave = tid >> 6, lane = tid & 63, qd = lane >> 4, ln = lane & 15;
  const size_t rowbase = (size_t)(b * SEQ + c * CHK);
  {
    int tt = tid >> 2, f0 = (tid & 3) * 4;
    float4 vq = *(const float4*)&qkw[(rowbase + tt) * QKS + h * FEAT + f0];
    float4 vk = *(const float4*)&qkw[(rowbase + tt) * QKS + 256 + h * FEAT + f0];
    ql[tt][f0] = vq.x; ql[tt][f0 + 1] = vq.y; ql[tt][f0 + 2] = vq.z; ql[tt][f0 + 3] = vq.w;
    kl[tt][f0] = vk.x; kl[tt][f0 + 1] = vk.y; kl[tt][f0 + 2] = vk.z; kl[tt][f0 + 3] = vk.w;
  }
  for (int i = tid; i < 512; i += 256) {
    int tt = i >> 3, db = (i & 7) * 8;
    union { uint4 v; u16 s[8]; } u;
    u.v = *(const uint4*)&vb[(rowbase + tt) * DM + h * HD + db];
#pragma unroll
    for (int j = 0; j < 8; j++) vlT[db + j][tt] = u.s[j];
  }
  const size_t cbase = (size_t)(bh * NC + c);
  for (int e = tid; e < EXPP; e += 256) kstl[e] = ck[cbase * EXPP + e];
  __syncthreads();
  f32x4 accA[4], accO[4];
#pragma unroll
  for (int mt = 0; mt < 4; mt++) { accA[mt] = (f32x4){0.f,0.f,0.f,0.f}; accO[mt] = (f32x4){0.f,0.f,0.f,0.f}; }
  const size_t sbase = cbase * EXPP * HD;
  const int kr = tid >> 3, db2 = (tid & 7) * 8;
  for (int kt = 0; kt < 9; kt++) {
    for (int i = tid; i < 2048; i += 256) {
      int tt = i >> 5, el = i & 31;
      int e = kt * 32 + el;
      float qv, kv;
      if (e == 0) { qv = 1.f; kv = 1.f; }
      else if (e < 17) { qv = 0.5f * ql[tt][e - 1]; kv = 0.5f * kl[tt][e - 1]; }
      else if (e < EXPD) {
        int u = e - 17, i0 = u >> 4, j0 = u & 15;
        qv = C2 * ql[tt][i0] * ql[tt][j0];
        kv = C2 * kl[tt][i0] * kl[tt][j0];
      } else { qv = 0.f; kv = 0.f; }
      qf[tt][el] = f2b(qv); kf[tt][el] = f2b(kv);
    }
    {
      union { uint4 v; u16 s[8]; } u;
      u.v = *(const uint4*)&ckv[sbase + (size_t)(kt * 32 + kr) * HD + db2];
#pragma unroll
      for (int j = 0; j < 8; j++) stT[db2 + j][kr] = u.s[j];
    }
    __syncthreads();
    bf16x8 bA = *(const bf16x8*)&kf[wave * 16 + ln][qd * 8];
    bf16x8 bO = *(const bf16x8*)&stT[wave * 16 + ln][qd * 8];
#pragma unroll
    for (int mt = 0; mt < 4; mt++) {
      bf16x8 a = *(const bf16x8*)&qf[mt * 16 + ln][qd * 8];
      accA[mt] = __builtin_amdgcn_mfma_f32_16x16x32_bf16(a, bA, accA[mt], 0, 0, 0);
      accO[mt] = __builtin_amdgcn_mfma_f32_16x16x32_bf16(a, bO, accO[mt], 0, 0, 0);
    }
    __syncthreads();
  }
  // write masked scores (overlays qf/kf — last reads completed at loop-end barrier)
#pragma unroll
  for (int mt = 0; mt < 4; mt++)
#pragma unroll
    for (int r = 0; r < 4; r++) {
      int t = mt * 16 + qd * 4 + r, s = wave * 16 + ln;
      al[t][s] = f2b((s <= t) ? accA[mt][r] : 0.f);
    }
  __syncthreads();
#pragma unroll
  for (int kk = 0; kk < 64; kk += 32) {
    bf16x8 bb = *(const bf16x8*)&vlT[wave * 16 + ln][kk + qd * 8];
#pragma unroll
    for (int mt = 0; mt < 4; mt++) {
      bf16x8 a = *(const bf16x8*)&al[mt * 16 + ln][kk + qd * 8];
      accO[mt] = __builtin_amdgcn_mfma_f32_16x16x32_bf16(a, bb, accO[mt], 0, 0, 0);
    }
  }
  {
    int t = tid >> 2, p = tid & 3;
    float q16[16];
#pragma unroll
    for (int j = 0; j < 16; j++) q16[j] = ql[t][j];
    float s = 0.f;
#pragma unroll
    for (int i2 = 0; i2 < 4; i2++) {
      int i = p * 4 + i2;
      float inner = 0.f;
#pragma unroll
      for (int j = 0; j < 16; j++) inner += q16[j] * kstl[17 + i * 16 + j];
      s += q16[i] * inner;
    }
    s *= C2;
    float s1 = 0.f;
#pragma unroll
    for (int j2 = 0; j2 < 4; j2++) { int j = p * 4 + j2; s1 += q16[j] * kstl[1 + j]; }
    s += 0.5f * s1;
    if (p == 0) s += kstl[0] + 1e-6f;
    float da = 0.f;
#pragma unroll
    for (int s2 = 0; s2 < 16; s2++) da += b2f(al[t][p * 16 + s2]);
    s += da;
    s += __shfl_xor(s, 1);
    s += __shfl_xor(s, 2);
    if (p == 0) denl[t] = s;
  }
  __syncthreads();
#pragma unroll
  for (int mt = 0; mt < 4; mt++)
#pragma unroll
    for (int r = 0; r < 4; r++) {
      int t = mt * 16 + qd * 4 + r;
      int hd = wave * 16 + ln;
      ob[(rowbase + t) * DM + h * HD + hd] = f2b(accO[mt][r] / denl[t]);
    }
}

extern "C" void kernel_launch(void* const* d_in, const int* in_sizes, int n_in,
                              void* d_out, int out_size, void* d_ws, size_t ws_size,
                              hipStream_t stream) {
  (void)in_sizes; (void)n_in; (void)out_size;
  const float* x   = (const float*)d_in[0];
  const float* kv0 = (const float*)d_in[1];
  const float* k0  = (const float*)d_in[2];
  const float* bq  = (const float*)d_in[4];
  const float* bk  = (const float*)d_in[6];
  const float* bv  = (const float*)d_in[8];
  const float* bo  = (const float*)d_in[10];
  float* out = (float*)d_out;
  char* ws = (char*)d_ws;
  size_t off = 0;
  auto take = [&](size_t bytes) { char* p = ws + off; off += (bytes + 255) & ~(size_t)255; return p; };
  u16*   xb   = (u16*)  take((size_t)BATCH * SEQ * DM * 2);
  u16*   wqkT = (u16*)  take((size_t)QKS * DM * 2);
  u16*   wvT  = (u16*)  take((size_t)DM * DM * 2);
  u16*   woT  = (u16*)  take((size_t)DM * DM * 2);
  float* bqk  = (float*)take((size_t)QKS * 4);
  float* qkw  = (float*)take((size_t)BATCH * SEQ * QKS * 4);
  u16*   vb   = (u16*)  take((size_t)BATCH * SEQ * DM * 2);
  u16*   ckv  = (u16*)  take((size_t)BH * NC * EXPP * HD * 2);
  float* ck   = (float*)take((size_t)BH * NC * EXPP * 4);
  u16*   ob   = (u16*)  take((size_t)BATCH * SEQ * DM * 2);
  if (off > ws_size) return;

  castk<<<(BATCH * SEQ * DM / 4 + 255) / 256, 256, 0, stream>>>(x, xb, BATCH * SEQ * DM / 4);
  castT<<<dim3(8, 32),  256, 0, stream>>>((const float*)d_in[3], wqkT,                DM, 256);
  castT<<<dim3(8, 32),  256, 0, stream>>>((const float*)d_in[5], wqkT + 256 * DM,     DM, 256);
  castT<<<dim3(32, 32), 256, 0, stream>>>((const float*)d_in[7], wvT,                 DM, DM);
  castT<<<dim3(32, 32), 256, 0, stream>>>((const float*)d_in[9], woT,                 DM, DM);
  concatb<<<2, 256, 0, stream>>>(bq, bk, bqk);

  gemm128<<<dim3(4, 64), 256, 0, stream>>>(xb, wqkT, bqk, BATCH * SEQ, QKS, DM, qkw, nullptr);
  gemm128<<<dim3(8, 64), 256, 0, stream>>>(xb, wvT,  bv,  BATCH * SEQ, DM,  DM, nullptr, vb);

  chunk_sums<<<BH * NC, 256, 0, stream>>>(qkw, vb, ckv, ck);
  kv_prefix<<<BH * 4, 256, 0, stream>>>(ckv, kv0, out + (size_t)BATCH * SEQ * DM);
  kst_prefix<<<BH, 256, 0, stream>>>(ck, k0, out + (size_t)BATCH * SEQ * DM + (size_t)BH * EXPD * HD);
  out_chunk<<<BH * NC, 256, 0, stream>>>(qkw, vb, ckv, ck, ob);

  gemm128<<<dim3(8, 64), 256, 0, stream>>>(ob, woT, bo, BATCH * SEQ, DM, DM, out, nullptr);
}

// Round 3
// 348.969 us; speedup vs baseline: 1.6862x; 1.1470x over previous
//
#include <hip/hip_runtime.h>

typedef unsigned short u16;
typedef __attribute__((ext_vector_type(8))) short bf16x8;
typedef __attribute__((ext_vector_type(4))) float f32x4;

#define BATCH 4
#define SEQ   2048
#define DM    1024
#define HEADS 16
#define FEAT  16
#define HD    64
#define EXPD  273
#define EXPP  288   // padded to multiple of 32 for MFMA K
#define CHK   64
#define NC    32    // SEQ / CHK
#define BH    64    // BATCH*HEADS
#define QKS   512   // fused QK projection row stride
#define C2    0.17677669529663687f  // 1/(sqrt(2)*sqrt(16))

__device__ __forceinline__ u16 f2b(float f) {
  union { float f; unsigned u; } v; v.f = f;
  unsigned u = v.u;
  return (u16)((u + 0x7fffu + ((u >> 16) & 1u)) >> 16);
}
__device__ __forceinline__ float b2f(u16 s) {
  union { unsigned u; float f; } v; v.u = ((unsigned)s) << 16; return v.f;
}

typedef const unsigned int __attribute__((address_space(1)))* gas1;
typedef unsigned int __attribute__((address_space(3)))* las3;
__device__ __forceinline__ void gl_lds16(const u16* g, u16* l) {
  __builtin_amdgcn_global_load_lds((gas1)(const void*)g, (las3)(void*)l, 16, 0, 0);
}

__global__ __launch_bounds__(256) void castk(const float* __restrict__ in, u16* __restrict__ out, int n4) {
  int i = blockIdx.x * 256 + threadIdx.x;
  if (i < n4) {
    float4 v = ((const float4*)in)[i];
    u16 r[4] = {f2b(v.x), f2b(v.y), f2b(v.z), f2b(v.w)};
    ((uint2*)out)[i] = *(uint2*)r;
  }
}

// in: [K][N] fp32 row-major -> out: [N][K] bf16 row-major
__global__ __launch_bounds__(256) void castT(const float* __restrict__ in, u16* __restrict__ out, int K, int N) {
  __shared__ float tile[32][33];
  int n0 = blockIdx.x * 32, k0 = blockIdx.y * 32;
  int tx = threadIdx.x & 31, ty = threadIdx.x >> 5;
  for (int i = ty; i < 32; i += 8)
    tile[i][tx] = in[(size_t)(k0 + i) * N + n0 + tx];
  __syncthreads();
  for (int i = ty; i < 32; i += 8)
    out[(size_t)(n0 + i) * K + k0 + tx] = f2b(tile[tx][i]);
}

__global__ __launch_bounds__(256) void concatb(const float* __restrict__ a, const float* __restrict__ b,
                                               float* __restrict__ o) {
  int i = blockIdx.x * 256 + threadIdx.x;
  if (i < 256) o[i] = a[i];
  else if (i < 512) o[i] = b[i - 256];
}

// C = A(MxK bf16 rm) @ BT^T + bias.  BT is [N][K] bf16 row-major.
// 128x128 tile, BK=32, 4 waves (2x2), global_load_lds staging (m97 structure).
__global__ __launch_bounds__(256) void gemm128(const u16* __restrict__ A, const u16* __restrict__ BT,
                                               const float* __restrict__ bias, int M, int N, int K,
                                               float* __restrict__ outF, u16* __restrict__ outB) {
  __shared__ __align__(16) u16 As[128 * 32];
  __shared__ __align__(16) u16 Bs[128 * 32];
  const int tid = threadIdx.x;
  const int wave = tid >> 6, lane = tid & 63, qd = lane >> 4, ln = lane & 15;
  const int wr = (wave >> 1) * 64, wc = (wave & 1) * 64;
  const int m0 = blockIdx.y * 128, n0 = blockIdx.x * 128;
  f32x4 acc[4][4];
#pragma unroll
  for (int i = 0; i < 4; i++)
#pragma unroll
    for (int j = 0; j < 4; j++) acc[i][j] = (f32x4){0.f, 0.f, 0.f, 0.f};
  const int sr = tid >> 2, sk = (tid & 3) * 8;
  const u16* gA0 = A + (size_t)(m0 + sr) * K + sk;
  const u16* gA1 = A + (size_t)(m0 + 64 + sr) * K + sk;
  const u16* gB0 = BT + (size_t)(n0 + sr) * K + sk;
  const u16* gB1 = BT + (size_t)(n0 + 64 + sr) * K + sk;
  u16* lA0 = &As[(size_t)(wave * 64) * 8];
  u16* lA1 = &As[(size_t)(256 + wave * 64) * 8];
  u16* lB0 = &Bs[(size_t)(wave * 64) * 8];
  u16* lB1 = &Bs[(size_t)(256 + wave * 64) * 8];
  for (int kk = 0; kk < K; kk += 32) {
    gl_lds16(gA0 + kk, lA0);
    gl_lds16(gA1 + kk, lA1);
    gl_lds16(gB0 + kk, lB0);
    gl_lds16(gB1 + kk, lB1);
    __syncthreads();
    bf16x8 af[4], bf[4];
#pragma unroll
    for (int t = 0; t < 4; t++) {
      af[t] = *(const bf16x8*)&As[(wr + t * 16 + ln) * 32 + qd * 8];
      bf[t] = *(const bf16x8*)&Bs[(wc + t * 16 + ln) * 32 + qd * 8];
    }
#pragma unroll
    for (int mt = 0; mt < 4; mt++)
#pragma unroll
      for (int nt = 0; nt < 4; nt++)
        acc[mt][nt] = __builtin_amdgcn_mfma_f32_16x16x32_bf16(af[mt], bf[nt], acc[mt][nt], 0, 0, 0);
    __syncthreads();
  }
#pragma unroll
  for (int nt = 0; nt < 4; nt++) {
    int col = n0 + wc + nt * 16 + ln;
    float bv = bias[col];
#pragma unroll
    for (int mt = 0; mt < 4; mt++) {
#pragma unroll
      for (int r = 0; r < 4; r++) {
        int row = m0 + wr + mt * 16 + qd * 4 + r;
        float v = acc[mt][nt][r] + bv;
        if (outF) outF[(size_t)row * N + col] = v;
        else      outB[(size_t)row * N + col] = f2b(v);
      }
    }
  }
}

// Per (b,h,chunk): ckv[e][hd] = sum_t Kf[t][e]*V[t][hd] (bf16), ck[e] = colsum Kf (fp32)
// Waves own e-tiles (private kfT buffers) -> single barrier per block.
__global__ __launch_bounds__(256) void chunk_sums(const float* __restrict__ qkw, const u16* __restrict__ vb,
                                                  u16* __restrict__ ckv, float* __restrict__ ck) {
  __shared__ float kl[64][17];
  __shared__ u16 vlT[64][72];    // [hd][t]
  __shared__ __align__(16) u16 kfT[4][16][72];  // per-wave [e_local][t]
  const int tid = threadIdx.x;
  const int bh = blockIdx.x / NC, c = blockIdx.x % NC;
  const int b = bh >> 4, h = bh & 15;
  const int wave = tid >> 6, lane = tid & 63, qd = lane >> 4, ln = lane & 15;
  const size_t rowbase = (size_t)(b * SEQ + c * CHK);
  {
    int tt = tid >> 2, f0 = (tid & 3) * 4;
    float4 v = *(const float4*)&qkw[(rowbase + tt) * QKS + 256 + h * FEAT + f0];
    kl[tt][f0] = v.x; kl[tt][f0 + 1] = v.y; kl[tt][f0 + 2] = v.z; kl[tt][f0 + 3] = v.w;
  }
  for (int i = tid; i < 512; i += 256) {
    int tt = i >> 3, db = (i & 7) * 8;
    union { uint4 v; u16 s[8]; } u;
    u.v = *(const uint4*)&vb[(rowbase + tt) * DM + h * HD + db];
#pragma unroll
    for (int j = 0; j < 8; j++) vlT[db + j][tt] = u.s[j];
  }
  __syncthreads();
  const size_t obase = (size_t)(bh * NC + c) * EXPP * HD;
  for (int mt = wave; mt < 18; mt += 4) {
#pragma unroll
    for (int el = 0; el < 16; el++) {
      int e = mt * 16 + el;
      float val;
      if (e == 0) val = 1.0f;
      else if (e < 17) val = 0.5f * kl[lane][e - 1];
      else if (e < EXPD) { int u = e - 17; val = C2 * kl[lane][u >> 4] * kl[lane][u & 15]; }
      else val = 0.0f;
      kfT[wave][el][lane] = f2b(val);
    }
    f32x4 acc[4];
#pragma unroll
    for (int nt = 0; nt < 4; nt++) acc[nt] = (f32x4){0.f, 0.f, 0.f, 0.f};
#pragma unroll
    for (int kk = 0; kk < 64; kk += 32) {
      bf16x8 a = *(const bf16x8*)&kfT[wave][ln][kk + qd * 8];
#pragma unroll
      for (int nt = 0; nt < 4; nt++) {
        bf16x8 bb = *(const bf16x8*)&vlT[nt * 16 + ln][kk + qd * 8];
        acc[nt] = __builtin_amdgcn_mfma_f32_16x16x32_bf16(a, bb, acc[nt], 0, 0, 0);
      }
    }
#pragma unroll
    for (int nt = 0; nt < 4; nt++)
#pragma unroll
      for (int r = 0; r < 4; r++) {
        int e = mt * 16 + qd * 4 + r;
        ckv[obase + (size_t)e * HD + nt * 16 + ln] = f2b(acc[nt][r]);
      }
  }
  for (int e = tid; e < EXPP; e += 256) {
    float s = 0.f;
    if (e == 0) s = 64.f;
    else if (e < 17) { float t = 0.f; for (int tt = 0; tt < 64; tt++) t += kl[tt][e - 1]; s = 0.5f * t; }
    else if (e < EXPD) {
      int u = e - 17, i0 = u >> 4, j0 = u & 15; float t = 0.f;
      for (int tt = 0; tt < 64; tt++) t += kl[tt][i0] * kl[tt][j0];
      s = C2 * t;
    }
    ck[(size_t)(bh * NC + c) * EXPP + e] = s;
  }
}

// Exclusive prefix over chunks (in place, bf16); final inclusive state (+input kv_state) -> d_out.
// Coalesced: thread = (bh, e, hd/8); wave covers 8 e-rows x 64 hd = 1KB contiguous per access.
// One-chunk-ahead prefetch keeps a load in flight across the 32-step scan.
__global__ __launch_bounds__(256) void kv_prefix(u16* __restrict__ ckv, const float* __restrict__ kv0,
                                                 float* __restrict__ out_kv) {
  const int tid = threadIdx.x;
  const int bh = blockIdx.x / 9, eg = blockIdx.x % 9;
  const int e = eg * 32 + (tid >> 3);
  const int hd = (tid & 7) * 8;
  float S[8];
  if (e < EXPD) {
    const float* p = &kv0[((size_t)bh * EXPD + e) * HD + hd];
    float4 a = *(const float4*)p;
    float4 b = *(const float4*)(p + 4);
    S[0] = a.x; S[1] = a.y; S[2] = a.z; S[3] = a.w;
    S[4] = b.x; S[5] = b.y; S[6] = b.z; S[7] = b.w;
  } else {
#pragma unroll
    for (int j = 0; j < 8; j++) S[j] = 0.f;
  }
  u16* base = ckv + (size_t)bh * NC * EXPP * HD + (size_t)e * HD + hd;
  const size_t cstride = (size_t)EXPP * HD;
  uint4 v = *(const uint4*)base;
  for (int c = 0; c < NC; c++) {
    uint4 vn;
    if (c + 1 < NC) vn = *(const uint4*)(base + (size_t)(c + 1) * cstride);
    union { uint4 q; u16 s[8]; } pk;
#pragma unroll
    for (int j = 0; j < 8; j++) pk.s[j] = f2b(S[j]);
    *(uint4*)(base + (size_t)c * cstride) = pk.q;
    union { uint4 q; u16 s[8]; } vv; vv.q = v;
#pragma unroll
    for (int j = 0; j < 8; j++) S[j] += b2f(vv.s[j]);
    v = vn;
  }
  if (e < EXPD) {
    float* o = &out_kv[((size_t)bh * EXPD + e) * HD + hd];
    float4 a, b;
    a.x = S[0]; a.y = S[1]; a.z = S[2]; a.w = S[3];
    b.x = S[4]; b.y = S[5]; b.z = S[6]; b.w = S[7];
    *(float4*)o = a;
    *(float4*)(o + 4) = b;
  }
}

__global__ __launch_bounds__(256) void kst_prefix(float* __restrict__ ck, const float* __restrict__ k0,
                                                  float* __restrict__ out_k) {
  const int bh = blockIdx.x;
  for (int e = threadIdx.x; e < EXPP; e += 256) {
    float S = (e < EXPD) ? k0[(size_t)bh * EXPD + e] : 0.f;
    for (int c = 0; c < NC; c++) {
      size_t idx = (size_t)(bh * NC + c) * EXPP + e;
      float v = ck[idx];
      ck[idx] = S;
      S += v;
    }
    if (e < EXPD) out_k[(size_t)bh * EXPD + e] = S;
  }
}

// Per (b,h,chunk): O = (Qf@S + mask_incl(Qf Kf^T)@V) / den
__global__ __launch_bounds__(256) void out_chunk(const float* __restrict__ qkw, const u16* __restrict__ vb,
                                                 const u16* __restrict__ ckv, const float* __restrict__ ck,
                                                 u16* __restrict__ ob) {
  __shared__ float ql[64][17];
  __shared__ float kl[64][17];
  __shared__ u16 vlT[64][72];                   // [hd][t]
  __shared__ __align__(16) char pool[10240];    // qf[64][40] + kf[64][40]; al[64][72] overlays
  __shared__ __align__(16) u16 stT[64][40];     // [hd][e_local]
  __shared__ float kstl[EXPP];
  __shared__ float denl[64];
  u16 (*qf)[40] = (u16(*)[40])pool;
  u16 (*kf)[40] = (u16(*)[40])(pool + 5120);
  u16 (*al)[72] = (u16(*)[72])pool;
  const int tid = threadIdx.x;
  const int bh = blockIdx.x / NC, c = blockIdx.x % NC;
  const int b = bh >> 4, h = bh & 15;
  const int wave = tid >> 6, lane = tid & 63, qd = lane >> 4, ln = lane & 15;
  const size_t rowbase = (size_t)(b * SEQ + c * CHK);
  {
    int tt = tid >> 2, f0 = (tid & 3) * 4;
    float4 vq = *(const float4*)&qkw[(rowbase + tt) * QKS + h * FEAT + f0];
    float4 vk = *(const float4*)&qkw[(rowbase + tt) * QKS + 256 + h * FEAT + f0];
    ql[tt][f0] = vq.x; ql[tt][f0 + 1] = vq.y; ql[tt][f0 + 2] = vq.z; ql[tt][f0 + 3] = vq.w;
    kl[tt][f0] = vk.x; kl[tt][f0 + 1] = vk.y; kl[tt][f0 + 2] = vk.z; kl[tt][f0 + 3] = vk.w;
  }
  for (int i = tid; i < 512; i += 256) {
    int tt = i >> 3, db = (i & 7) * 8;
    union { uint4 v; u16 s[8]; } u;
    u.v = *(const uint4*)&vb[(rowbase + tt) * DM + h * HD + db];
#pragma unroll
    for (int j = 0; j < 8; j++) vlT[db + j][tt] = u.s[j];
  }
  const size_t cbase = (size_t)(bh * NC + c);
  for (int e = tid; e < EXPP; e += 256) kstl[e] = ck[cbase * EXPP + e];
  __syncthreads();
  f32x4 accA[4], accO[4];
#pragma unroll
  for (int mt = 0; mt < 4; mt++) { accA[mt] = (f32x4){0.f,0.f,0.f,0.f}; accO[mt] = (f32x4){0.f,0.f,0.f,0.f}; }
  const size_t sbase = cbase * EXPP * HD;
  const int kr = tid >> 3, db2 = (tid & 7) * 8;
  for (int kt = 0; kt < 9; kt++) {
    for (int i = tid; i < 2048; i += 256) {
      int tt = i >> 5, el = i & 31;
      int e = kt * 32 + el;
      float qv, kv;
      if (e == 0) { qv = 1.f; kv = 1.f; }
      else if (e < 17) { qv = 0.5f * ql[tt][e - 1]; kv = 0.5f * kl[tt][e - 1]; }
      else if (e < EXPD) {
        int u = e - 17, i0 = u >> 4, j0 = u & 15;
        qv = C2 * ql[tt][i0] * ql[tt][j0];
        kv = C2 * kl[tt][i0] * kl[tt][j0];
      } else { qv = 0.f; kv = 0.f; }
      qf[tt][el] = f2b(qv); kf[tt][el] = f2b(kv);
    }
    {
      union { uint4 v; u16 s[8]; } u;
      u.v = *(const uint4*)&ckv[sbase + (size_t)(kt * 32 + kr) * HD + db2];
#pragma unroll
      for (int j = 0; j < 8; j++) stT[db2 + j][kr] = u.s[j];
    }
    __syncthreads();
    bf16x8 bA = *(const bf16x8*)&kf[wave * 16 + ln][qd * 8];
    bf16x8 bO = *(const bf16x8*)&stT[wave * 16 + ln][qd * 8];
#pragma unroll
    for (int mt = 0; mt < 4; mt++) {
      bf16x8 a = *(const bf16x8*)&qf[mt * 16 + ln][qd * 8];
      accA[mt] = __builtin_amdgcn_mfma_f32_16x16x32_bf16(a, bA, accA[mt], 0, 0, 0);
      accO[mt] = __builtin_amdgcn_mfma_f32_16x16x32_bf16(a, bO, accO[mt], 0, 0, 0);
    }
    __syncthreads();
  }
  // write masked scores (overlays qf/kf — last reads completed at loop-end barrier)
#pragma unroll
  for (int mt = 0; mt < 4; mt++)
#pragma unroll
    for (int r = 0; r < 4; r++) {
      int t = mt * 16 + qd * 4 + r, s = wave * 16 + ln;
      al[t][s] = f2b((s <= t) ? accA[mt][r] : 0.f);
    }
  __syncthreads();
#pragma unroll
  for (int kk = 0; kk < 64; kk += 32) {
    bf16x8 bb = *(const bf16x8*)&vlT[wave * 16 + ln][kk + qd * 8];
#pragma unroll
    for (int mt = 0; mt < 4; mt++) {
      bf16x8 a = *(const bf16x8*)&al[mt * 16 + ln][kk + qd * 8];
      accO[mt] = __builtin_amdgcn_mfma_f32_16x16x32_bf16(a, bb, accO[mt], 0, 0, 0);
    }
  }
  {
    int t = tid >> 2, p = tid & 3;
    float q16[16];
#pragma unroll
    for (int j = 0; j < 16; j++) q16[j] = ql[t][j];
    float s = 0.f;
#pragma unroll
    for (int i2 = 0; i2 < 4; i2++) {
      int i = p * 4 + i2;
      float inner = 0.f;
#pragma unroll
      for (int j = 0; j < 16; j++) inner += q16[j] * kstl[17 + i * 16 + j];
      s += q16[i] * inner;
    }
    s *= C2;
    float s1 = 0.f;
#pragma unroll
    for (int j2 = 0; j2 < 4; j2++) { int j = p * 4 + j2; s1 += q16[j] * kstl[1 + j]; }
    s += 0.5f * s1;
    if (p == 0) s += kstl[0] + 1e-6f;
    float da = 0.f;
#pragma unroll
    for (int s2 = 0; s2 < 16; s2++) da += b2f(al[t][p * 16 + s2]);
    s += da;
    s += __shfl_xor(s, 1);
    s += __shfl_xor(s, 2);
    if (p == 0) denl[t] = s;
  }
  __syncthreads();
#pragma unroll
  for (int mt = 0; mt < 4; mt++)
#pragma unroll
    for (int r = 0; r < 4; r++) {
      int t = mt * 16 + qd * 4 + r;
      int hd = wave * 16 + ln;
      ob[(rowbase + t) * DM + h * HD + hd] = f2b(accO[mt][r] / denl[t]);
    }
}

extern "C" void kernel_launch(void* const* d_in, const int* in_sizes, int n_in,
                              void* d_out, int out_size, void* d_ws, size_t ws_size,
                              hipStream_t stream) {
  (void)in_sizes; (void)n_in; (void)out_size;
  const float* x   = (const float*)d_in[0];
  const float* kv0 = (const float*)d_in[1];
  const float* k0  = (const float*)d_in[2];
  const float* bq  = (const float*)d_in[4];
  const float* bk  = (const float*)d_in[6];
  const float* bv  = (const float*)d_in[8];
  const float* bo  = (const float*)d_in[10];
  float* out = (float*)d_out;
  char* ws = (char*)d_ws;
  size_t off = 0;
  auto take = [&](size_t bytes) { char* p = ws + off; off += (bytes + 255) & ~(size_t)255; return p; };
  u16*   xb   = (u16*)  take((size_t)BATCH * SEQ * DM * 2);
  u16*   wqkT = (u16*)  take((size_t)QKS * DM * 2);
  u16*   wvT  = (u16*)  take((size_t)DM * DM * 2);
  u16*   woT  = (u16*)  take((size_t)DM * DM * 2);
  float* bqk  = (float*)take((size_t)QKS * 4);
  float* qkw  = (float*)take((size_t)BATCH * SEQ * QKS * 4);
  u16*   vb   = (u16*)  take((size_t)BATCH * SEQ * DM * 2);
  u16*   ckv  = (u16*)  take((size_t)BH * NC * EXPP * HD * 2);
  float* ck   = (float*)take((size_t)BH * NC * EXPP * 4);
  u16*   ob   = (u16*)  take((size_t)BATCH * SEQ * DM * 2);
  if (off > ws_size) return;

  castk<<<(BATCH * SEQ * DM / 4 + 255) / 256, 256, 0, stream>>>(x, xb, BATCH * SEQ * DM / 4);
  castT<<<dim3(8, 32),  256, 0, stream>>>((const float*)d_in[3], wqkT,                DM, 256);
  castT<<<dim3(8, 32),  256, 0, stream>>>((const float*)d_in[5], wqkT + 256 * DM,     DM, 256);
  castT<<<dim3(32, 32), 256, 0, stream>>>((const float*)d_in[7], wvT,                 DM, DM);
  castT<<<dim3(32, 32), 256, 0, stream>>>((const float*)d_in[9], woT,                 DM, DM);
  concatb<<<2, 256, 0, stream>>>(bq, bk, bqk);

  gemm128<<<dim3(4, 64), 256, 0, stream>>>(xb, wqkT, bqk, BATCH * SEQ, QKS, DM, qkw, nullptr);
  gemm128<<<dim3(8, 64), 256, 0, stream>>>(xb, wvT,  bv,  BATCH * SEQ, DM,  DM, nullptr, vb);

  chunk_sums<<<BH * NC, 256, 0, stream>>>(qkw, vb, ckv, ck);
  kv_prefix<<<BH * 9, 256, 0, stream>>>(ckv, kv0, out + (size_t)BATCH * SEQ * DM);
  kst_prefix<<<BH, 256, 0, stream>>>(ck, k0, out + (size_t)BATCH * SEQ * DM + (size_t)BH * EXPD * HD);
  out_chunk<<<BH * NC, 256, 0, stream>>>(qkw, vb, ckv, ck, ob);

  gemm128<<<dim3(8, 64), 256, 0, stream>>>(ob, woT, bo, BATCH * SEQ, DM, DM, out, nullptr);
}

// Round 4
// 335.749 us; speedup vs baseline: 1.7526x; 1.0394x over previous
//
#include <hip/hip_runtime.h>

typedef unsigned short u16;
typedef __attribute__((ext_vector_type(8))) short bf16x8;
typedef __attribute__((ext_vector_type(4))) float f32x4;

#define BATCH 4
#define SEQ   2048
#define DM    1024
#define HEADS 16
#define FEAT  16
#define HD    64
#define EXPD  273
#define EXPP  288   // padded to multiple of 32 for MFMA K
#define CHK   64
#define NC    32    // SEQ / CHK
#define BH    64    // BATCH*HEADS
#define QKS   512   // fused QK projection row stride
#define MROWS 8192  // BATCH*SEQ
#define C2    0.17677669529663687f  // 1/(sqrt(2)*sqrt(16))

__device__ __forceinline__ u16 f2b(float f) {
  union { float f; unsigned u; } v; v.f = f;
  unsigned u = v.u;
  return (u16)((u + 0x7fffu + ((u >> 16) & 1u)) >> 16);
}
__device__ __forceinline__ float b2f(u16 s) {
  union { unsigned u; float f; } v; v.u = ((unsigned)s) << 16; return v.f;
}

typedef const unsigned int __attribute__((address_space(1)))* gas1;
typedef unsigned int __attribute__((address_space(3)))* las3;
__device__ __forceinline__ void gl_lds16(const u16* g, u16* l) {
  __builtin_amdgcn_global_load_lds((gas1)(const void*)g, (las3)(void*)l, 16, 0, 0);
}

__global__ __launch_bounds__(256) void castk(const float* __restrict__ in, u16* __restrict__ out, int n4) {
  int i = blockIdx.x * 256 + threadIdx.x;
  if (i < n4) {
    float4 v = ((const float4*)in)[i];
    u16 r[4] = {f2b(v.x), f2b(v.y), f2b(v.z), f2b(v.w)};
    ((uint2*)out)[i] = *(uint2*)r;
  }
}

// in: [K][N] fp32 row-major -> out: [N][K] bf16 row-major
__global__ __launch_bounds__(256) void castT(const float* __restrict__ in, u16* __restrict__ out, int K, int N) {
  __shared__ float tile[32][33];
  int n0 = blockIdx.x * 32, k0 = blockIdx.y * 32;
  int tx = threadIdx.x & 31, ty = threadIdx.x >> 5;
  for (int i = ty; i < 32; i += 8)
    tile[i][tx] = in[(size_t)(k0 + i) * N + n0 + tx];
  __syncthreads();
  for (int i = ty; i < 32; i += 8)
    out[(size_t)(n0 + i) * K + k0 + tx] = f2b(tile[tx][i]);
}

__global__ __launch_bounds__(256) void concatb(const float* __restrict__ a, const float* __restrict__ b,
                                               float* __restrict__ o) {
  int i = blockIdx.x * 256 + threadIdx.x;
  if (i < 256) o[i] = a[i];
  else if (i < 512) o[i] = b[i - 256];
}

// C = A(MxK bf16 rm) @ BT^T + bias.  BT is [N][K] bf16 row-major.
// outF: fp32 rm; outB: bf16 rm; outT: bf16 TRANSPOSED [col*M + row] (packed uint2 stores).
__global__ __launch_bounds__(256) void gemm128(const u16* __restrict__ A, const u16* __restrict__ BT,
                                               const float* __restrict__ bias, int M, int N, int K,
                                               float* __restrict__ outF, u16* __restrict__ outB,
                                               u16* __restrict__ outT) {
  __shared__ __align__(16) u16 As[128 * 32];
  __shared__ __align__(16) u16 Bs[128 * 32];
  const int tid = threadIdx.x;
  const int wave = tid >> 6, lane = tid & 63, qd = lane >> 4, ln = lane & 15;
  const int wr = (wave >> 1) * 64, wc = (wave & 1) * 64;
  const int m0 = blockIdx.y * 128, n0 = blockIdx.x * 128;
  f32x4 acc[4][4];
#pragma unroll
  for (int i = 0; i < 4; i++)
#pragma unroll
    for (int j = 0; j < 4; j++) acc[i][j] = (f32x4){0.f, 0.f, 0.f, 0.f};
  const int sr = tid >> 2, sk = (tid & 3) * 8;
  const u16* gA0 = A + (size_t)(m0 + sr) * K + sk;
  const u16* gA1 = A + (size_t)(m0 + 64 + sr) * K + sk;
  const u16* gB0 = BT + (size_t)(n0 + sr) * K + sk;
  const u16* gB1 = BT + (size_t)(n0 + 64 + sr) * K + sk;
  u16* lA0 = &As[(size_t)(wave * 64) * 8];
  u16* lA1 = &As[(size_t)(256 + wave * 64) * 8];
  u16* lB0 = &Bs[(size_t)(wave * 64) * 8];
  u16* lB1 = &Bs[(size_t)(256 + wave * 64) * 8];
  for (int kk = 0; kk < K; kk += 32) {
    gl_lds16(gA0 + kk, lA0);
    gl_lds16(gA1 + kk, lA1);
    gl_lds16(gB0 + kk, lB0);
    gl_lds16(gB1 + kk, lB1);
    __syncthreads();
    bf16x8 af[4], bf[4];
#pragma unroll
    for (int t = 0; t < 4; t++) {
      af[t] = *(const bf16x8*)&As[(wr + t * 16 + ln) * 32 + qd * 8];
      bf[t] = *(const bf16x8*)&Bs[(wc + t * 16 + ln) * 32 + qd * 8];
    }
#pragma unroll
    for (int mt = 0; mt < 4; mt++)
#pragma unroll
      for (int nt = 0; nt < 4; nt++)
        acc[mt][nt] = __builtin_amdgcn_mfma_f32_16x16x32_bf16(af[mt], bf[nt], acc[mt][nt], 0, 0, 0);
    __syncthreads();
  }
  if (outT) {
#pragma unroll
    for (int nt = 0; nt < 4; nt++) {
      int col = n0 + wc + nt * 16 + ln;
      float bv = bias[col];
#pragma unroll
      for (int mt = 0; mt < 4; mt++) {
        u16 pk[4];
#pragma unroll
        for (int r = 0; r < 4; r++) pk[r] = f2b(acc[mt][nt][r] + bv);
        int row0 = m0 + wr + mt * 16 + qd * 4;
        *(uint2*)&outT[(size_t)col * M + row0] = *(uint2*)pk;
      }
    }
    return;
  }
#pragma unroll
  for (int nt = 0; nt < 4; nt++) {
    int col = n0 + wc + nt * 16 + ln;
    float bv = bias[col];
#pragma unroll
    for (int mt = 0; mt < 4; mt++) {
#pragma unroll
      for (int r = 0; r < 4; r++) {
        int row = m0 + wr + mt * 16 + qd * 4 + r;
        float v = acc[mt][nt][r] + bv;
        if (outF) outF[(size_t)row * N + col] = v;
        else      outB[(size_t)row * N + col] = f2b(v);
      }
    }
  }
}

// Per (b,h,chunk): ckvT[hd][e] = sum_t Kf[t][e]*V[t][hd] (bf16), ck[e] = colsum Kf (fp32)
// V B-frags loaded directly from vbT (global, coalesced 16B/lane). ckvT stores packed uint2.
__global__ __launch_bounds__(256) void chunk_sums(const float* __restrict__ qkw, const u16* __restrict__ vbT,
                                                  u16* __restrict__ ckvT, float* __restrict__ ck) {
  __shared__ float kl[64][17];
  __shared__ __align__(16) u16 kfT[4][16][72];  // per-wave [e_local][t]
  const int tid = threadIdx.x;
  const int bh = blockIdx.x / NC, c = blockIdx.x % NC;
  const int b = bh >> 4, h = bh & 15;
  const int wave = tid >> 6, lane = tid & 63, qd = lane >> 4, ln = lane & 15;
  const size_t rowbase = (size_t)(b * SEQ + c * CHK);
  {
    int tt = tid >> 2, f0 = (tid & 3) * 4;
    float4 v = *(const float4*)&qkw[(rowbase + tt) * QKS + 256 + h * FEAT + f0];
    kl[tt][f0] = v.x; kl[tt][f0 + 1] = v.y; kl[tt][f0 + 2] = v.z; kl[tt][f0 + 3] = v.w;
  }
  // prefetch V fragments from vbT [col=h*64+hd][row=b*2048+t]
  uint4 bVv[2][4];
#pragma unroll
  for (int kk2 = 0; kk2 < 2; kk2++)
#pragma unroll
    for (int nt = 0; nt < 4; nt++)
      bVv[kk2][nt] = *(const uint4*)&vbT[(size_t)(h * HD + nt * 16 + ln) * MROWS +
                                         (size_t)b * SEQ + c * CHK + kk2 * 32 + qd * 8];
  __syncthreads();
  const size_t obase = (size_t)(bh * NC + c) * HD;
  for (int mt = wave; mt < 18; mt += 4) {
#pragma unroll
    for (int el = 0; el < 16; el++) {
      int e = mt * 16 + el;
      float val;
      if (e == 0) val = 1.0f;
      else if (e < 17) val = 0.5f * kl[lane][e - 1];
      else if (e < EXPD) { int u = e - 17; val = C2 * kl[lane][u >> 4] * kl[lane][u & 15]; }
      else val = 0.0f;
      kfT[wave][el][lane] = f2b(val);
    }
    f32x4 acc[4];
#pragma unroll
    for (int nt = 0; nt < 4; nt++) acc[nt] = (f32x4){0.f, 0.f, 0.f, 0.f};
#pragma unroll
    for (int kk2 = 0; kk2 < 2; kk2++) {
      bf16x8 a = *(const bf16x8*)&kfT[wave][ln][kk2 * 32 + qd * 8];
#pragma unroll
      for (int nt = 0; nt < 4; nt++) {
        bf16x8 bb = *(const bf16x8*)&bVv[kk2][nt];
        acc[nt] = __builtin_amdgcn_mfma_f32_16x16x32_bf16(a, bb, acc[nt], 0, 0, 0);
      }
    }
#pragma unroll
    for (int nt = 0; nt < 4; nt++) {
      u16 pk[4];
#pragma unroll
      for (int r = 0; r < 4; r++) pk[r] = f2b(acc[nt][r]);
      *(uint2*)&ckvT[(obase + nt * 16 + ln) * EXPP + mt * 16 + qd * 4] = *(uint2*)pk;
    }
  }
  for (int e = tid; e < EXPP; e += 256) {
    float s = 0.f;
    if (e == 0) s = 64.f;
    else if (e < 17) { float t = 0.f; for (int tt = 0; tt < 64; tt++) t += kl[tt][e - 1]; s = 0.5f * t; }
    else if (e < EXPD) {
      int u = e - 17, i0 = u >> 4, j0 = u & 15; float t = 0.f;
      for (int tt = 0; tt < 64; tt++) t += kl[tt][i0] * kl[tt][j0];
      s = C2 * t;
    }
    ck[(size_t)(bh * NC + c) * EXPP + e] = s;
  }
}

// Exclusive prefix over chunks (in place, bf16) on ckvT [bh][c][hd][EXPP]; inclusive final -> d_out.
__global__ __launch_bounds__(256) void kv_prefix(u16* __restrict__ ckvT, const float* __restrict__ kv0,
                                                 float* __restrict__ out_kv) {
  const int tid = threadIdx.x;
  const int bh = blockIdx.x / 9, eg = blockIdx.x % 9;
  const int hd = tid >> 2;
  const int e0 = eg * 32 + (tid & 3) * 8;
  float S[8];
#pragma unroll
  for (int j = 0; j < 8; j++) {
    int e = e0 + j;
    S[j] = (e < EXPD) ? kv0[((size_t)bh * EXPD + e) * HD + hd] : 0.f;
  }
  u16* base = ckvT + ((size_t)bh * NC * HD + hd) * EXPP + e0;
  const size_t cstride = (size_t)HD * EXPP;
  uint4 v = *(const uint4*)base;
  for (int c = 0; c < NC; c++) {
    uint4 vn;
    if (c + 1 < NC) vn = *(const uint4*)(base + (size_t)(c + 1) * cstride);
    union { uint4 q; u16 s[8]; } pk;
#pragma unroll
    for (int j = 0; j < 8; j++) pk.s[j] = f2b(S[j]);
    *(uint4*)(base + (size_t)c * cstride) = pk.q;
    union { uint4 q; u16 s[8]; } vv; vv.q = v;
#pragma unroll
    for (int j = 0; j < 8; j++) S[j] += b2f(vv.s[j]);
    v = vn;
  }
#pragma unroll
  for (int j = 0; j < 8; j++) {
    int e = e0 + j;
    if (e < EXPD) out_kv[((size_t)bh * EXPD + e) * HD + hd] = S[j];
  }
}

__global__ __launch_bounds__(256) void kst_prefix(float* __restrict__ ck, const float* __restrict__ k0,
                                                  float* __restrict__ out_k) {
  const int bh = blockIdx.x;
  for (int e = threadIdx.x; e < EXPP; e += 256) {
    float S = (e < EXPD) ? k0[(size_t)bh * EXPD + e] : 0.f;
    for (int c = 0; c < NC; c++) {
      size_t idx = (size_t)(bh * NC + c) * EXPP + e;
      float v = ck[idx];
      ck[idx] = S;
      S += v;
    }
    if (e < EXPD) out_k[(size_t)bh * EXPD + e] = S;
  }
}

// Per (b,h,chunk): O = (Qf@S + mask_incl(poly(QK^T))@V) / den.
// Scores via poly identity: phi(q).phi(k) = 1 + u/4 + u^2/32, u = q.k (one MFMA per m-tile).
// S and V B-fragments prefetched directly from global (coalesced). Qf slab double-buffered.
__global__ __launch_bounds__(256) void out_chunk(const float* __restrict__ qkw, const u16* __restrict__ vbT,
                                                 const u16* __restrict__ ckvT, const float* __restrict__ ck,
                                                 u16* __restrict__ ob) {
  __shared__ float ql[64][17];
  __shared__ __align__(16) u16 qlb[64][40];      // bf16 q rows, cols 16..31 zero
  __shared__ __align__(16) u16 klb[64][40];
  __shared__ __align__(16) u16 qfs[2][64][40];   // Qf slab dbuf; al overlays after loop
  __shared__ float kstl[EXPP];
  __shared__ float denl[64];
  u16 (*al)[72] = (u16(*)[72])&qfs[0][0][0];     // 9216 B <= 20480 B
  const int tid = threadIdx.x;
  const int bh = blockIdx.x / NC, c = blockIdx.x % NC;
  const int b = bh >> 4, h = bh & 15;
  const int wave = tid >> 6, lane = tid & 63, qd = lane >> 4, ln = lane & 15;
  const size_t rowbase = (size_t)(b * SEQ + c * CHK);
  {
    int tt = tid >> 2, f0 = (tid & 3) * 4;
    float4 vq = *(const float4*)&qkw[(rowbase + tt) * QKS + h * FEAT + f0];
    float4 vk = *(const float4*)&qkw[(rowbase + tt) * QKS + 256 + h * FEAT + f0];
    ql[tt][f0] = vq.x; ql[tt][f0 + 1] = vq.y; ql[tt][f0 + 2] = vq.z; ql[tt][f0 + 3] = vq.w;
    u16 qb[4] = {f2b(vq.x), f2b(vq.y), f2b(vq.z), f2b(vq.w)};
    u16 kb[4] = {f2b(vk.x), f2b(vk.y), f2b(vk.z), f2b(vk.w)};
    *(uint2*)&qlb[tt][f0] = *(uint2*)qb;
    *(uint2*)&klb[tt][f0] = *(uint2*)kb;
    *(uint2*)&qlb[tt][16 + f0] = (uint2){0u, 0u};
    *(uint2*)&klb[tt][16 + f0] = (uint2){0u, 0u};
  }
  const size_t cbase = (size_t)(bh * NC + c);
  for (int e = tid; e < EXPP; e += 256) kstl[e] = ck[cbase * EXPP + e];
  // prefetch S fragments (exclusive-prefix state) and V fragments from global
  uint4 bSv[9];
  const u16* sptr = ckvT + (cbase * HD + wave * 16 + ln) * EXPP + qd * 8;
#pragma unroll
  for (int kt = 0; kt < 9; kt++) bSv[kt] = *(const uint4*)(sptr + kt * 32);
  uint4 bVv[2];
#pragma unroll
  for (int kk2 = 0; kk2 < 2; kk2++)
    bVv[kk2] = *(const uint4*)&vbT[(size_t)(h * HD + wave * 16 + ln) * MROWS +
                                   (size_t)b * SEQ + c * CHK + kk2 * 32 + qd * 8];

  auto feat = [&](int buf, int kt) {
#pragma unroll
    for (int ii = 0; ii < 8; ii++) {
      int i = tid + ii * 256;
      int tt = i >> 5, el = i & 31;
      int e = kt * 32 + el;
      float qv;
      if (e == 0) qv = 1.f;
      else if (e < 17) qv = 0.5f * ql[tt][e - 1];
      else if (e < EXPD) { int u = e - 17; qv = C2 * ql[tt][u >> 4] * ql[tt][u & 15]; }
      else qv = 0.f;
      qfs[buf][tt][el] = f2b(qv);
    }
  };

  __syncthreads();            // ql/qlb/klb/kstl visible
  feat(0, 0);
  // raw-dot MFMAs (scores): u = q.k
  f32x4 accU[4];
  {
    bf16x8 bU = *(const bf16x8*)&klb[wave * 16 + ln][qd * 8];
#pragma unroll
    for (int mt = 0; mt < 4; mt++) {
      bf16x8 aU = *(const bf16x8*)&qlb[mt * 16 + ln][qd * 8];
      accU[mt] = __builtin_amdgcn_mfma_f32_16x16x32_bf16(aU, bU, (f32x4){0.f, 0.f, 0.f, 0.f}, 0, 0, 0);
    }
  }
  __syncthreads();            // qfs[0] ready
  f32x4 accO[4];
#pragma unroll
  for (int mt = 0; mt < 4; mt++) accO[mt] = (f32x4){0.f, 0.f, 0.f, 0.f};
#pragma unroll
  for (int kt = 0; kt < 9; kt++) {
    int cur = kt & 1;
    if (kt < 8) feat(cur ^ 1, kt + 1);
    bf16x8 bS = *(const bf16x8*)&bSv[kt];
#pragma unroll
    for (int mt = 0; mt < 4; mt++) {
      bf16x8 a = *(const bf16x8*)&qfs[cur][mt * 16 + ln][qd * 8];
      accO[mt] = __builtin_amdgcn_mfma_f32_16x16x32_bf16(a, bS, accO[mt], 0, 0, 0);
    }
    __syncthreads();
  }
  // masked scores -> al (overlays qfs; all qfs reads done at final loop barrier)
#pragma unroll
  for (int mt = 0; mt < 4; mt++)
#pragma unroll
    for (int r = 0; r < 4; r++) {
      int t = mt * 16 + qd * 4 + r, s = wave * 16 + ln;
      float u = accU[mt][r];
      float sc = 1.f + 0.25f * u + 0.03125f * u * u;
      al[t][s] = f2b((s <= t) ? sc : 0.f);
    }
  __syncthreads();
  // A@V with V frags from registers
#pragma unroll
  for (int kk2 = 0; kk2 < 2; kk2++) {
    bf16x8 bb = *(const bf16x8*)&bVv[kk2];
#pragma unroll
    for (int mt = 0; mt < 4; mt++) {
      bf16x8 a = *(const bf16x8*)&al[mt * 16 + ln][kk2 * 32 + qd * 8];
      accO[mt] = __builtin_amdgcn_mfma_f32_16x16x32_bf16(a, bb, accO[mt], 0, 0, 0);
    }
  }
  // denominator
  {
    int t = tid >> 2, p = tid & 3;
    float q16[16];
#pragma unroll
    for (int j = 0; j < 16; j++) q16[j] = ql[t][j];
    float s = 0.f;
#pragma unroll
    for (int i2 = 0; i2 < 4; i2++) {
      int i = p * 4 + i2;
      float inner = 0.f;
#pragma unroll
      for (int j = 0; j < 16; j++) inner += q16[j] * kstl[17 + i * 16 + j];
      s += q16[i] * inner;
    }
    s *= C2;
    float s1 = 0.f;
#pragma unroll
    for (int j2 = 0; j2 < 4; j2++) { int j = p * 4 + j2; s1 += q16[j] * kstl[1 + j]; }
    s += 0.5f * s1;
    if (p == 0) s += kstl[0] + 1e-6f;
    float da = 0.f;
#pragma unroll
    for (int s2 = 0; s2 < 16; s2++) da += b2f(al[t][p * 16 + s2]);
    s += da;
    s += __shfl_xor(s, 1);
    s += __shfl_xor(s, 2);
    if (p == 0) denl[t] = s;
  }
  __syncthreads();
#pragma unroll
  for (int mt = 0; mt < 4; mt++)
#pragma unroll
    for (int r = 0; r < 4; r++) {
      int t = mt * 16 + qd * 4 + r;
      int hd = wave * 16 + ln;
      ob[(rowbase + t) * DM + h * HD + hd] = f2b(accO[mt][r] / denl[t]);
    }
}

extern "C" void kernel_launch(void* const* d_in, const int* in_sizes, int n_in,
                              void* d_out, int out_size, void* d_ws, size_t ws_size,
                              hipStream_t stream) {
  (void)in_sizes; (void)n_in; (void)out_size;
  const float* x   = (const float*)d_in[0];
  const float* kv0 = (const float*)d_in[1];
  const float* k0  = (const float*)d_in[2];
  const float* bq  = (const float*)d_in[4];
  const float* bk  = (const float*)d_in[6];
  const float* bv  = (const float*)d_in[8];
  const float* bo  = (const float*)d_in[10];
  float* out = (float*)d_out;
  char* ws = (char*)d_ws;
  size_t off = 0;
  auto take = [&](size_t bytes) { char* p = ws + off; off += (bytes + 255) & ~(size_t)255; return p; };
  u16*   xb   = (u16*)  take((size_t)BATCH * SEQ * DM * 2);
  u16*   wqkT = (u16*)  take((size_t)QKS * DM * 2);
  u16*   wvT  = (u16*)  take((size_t)DM * DM * 2);
  u16*   woT  = (u16*)  take((size_t)DM * DM * 2);
  float* bqk  = (float*)take((size_t)QKS * 4);
  float* qkw  = (float*)take((size_t)BATCH * SEQ * QKS * 4);
  u16*   vbT  = (u16*)  take((size_t)BATCH * SEQ * DM * 2);
  u16*   ckvT = (u16*)  take((size_t)BH * NC * EXPP * HD * 2);
  float* ck   = (float*)take((size_t)BH * NC * EXPP * 4);
  u16*   ob   = (u16*)  take((size_t)BATCH * SEQ * DM * 2);
  if (off > ws_size) return;

  castk<<<(BATCH * SEQ * DM / 4 + 255) / 256, 256, 0, stream>>>(x, xb, BATCH * SEQ * DM / 4);
  castT<<<dim3(8, 32),  256, 0, stream>>>((const float*)d_in[3], wqkT,            DM, 256);
  castT<<<dim3(8, 32),  256, 0, stream>>>((const float*)d_in[5], wqkT + 256 * DM, DM, 256);
  castT<<<dim3(32, 32), 256, 0, stream>>>((const float*)d_in[7], wvT,             DM, DM);
  castT<<<dim3(32, 32), 256, 0, stream>>>((const float*)d_in[9], woT,             DM, DM);
  concatb<<<2, 256, 0, stream>>>(bq, bk, bqk);

  gemm128<<<dim3(4, 64), 256, 0, stream>>>(xb, wqkT, bqk, MROWS, QKS, DM, qkw, nullptr, nullptr);
  gemm128<<<dim3(8, 64), 256, 0, stream>>>(xb, wvT,  bv,  MROWS, DM,  DM, nullptr, nullptr, vbT);

  chunk_sums<<<BH * NC, 256, 0, stream>>>(qkw, vbT, ckvT, ck);
  kv_prefix<<<BH * 9, 256, 0, stream>>>(ckvT, kv0, out + (size_t)BATCH * SEQ * DM);
  kst_prefix<<<BH, 256, 0, stream>>>(ck, k0, out + (size_t)BATCH * SEQ * DM + (size_t)BH * EXPD * HD);
  out_chunk<<<BH * NC, 256, 0, stream>>>(qkw, vbT, ckvT, ck, ob);

  gemm128<<<dim3(8, 64), 256, 0, stream>>>(ob, woT, bo, MROWS, DM, DM, out, nullptr, nullptr);
}

// Round 6
// 303.649 us; speedup vs baseline: 1.9379x; 1.1057x over previous
//
#include <hip/hip_runtime.h>

typedef unsigned short u16;
typedef __attribute__((ext_vector_type(8))) short bf16x8;
typedef __attribute__((ext_vector_type(4))) float f32x4;

#define BATCH 4
#define SEQ   2048
#define DM    1024
#define HEADS 16
#define FEAT  16
#define HD    64
#define EXPD  273
#define EXPP  288   // padded to multiple of 32 for MFMA K
#define CHK   128
#define NC    16    // SEQ / CHK
#define BH    64    // BATCH*HEADS
#define QKS   512   // fused QK projection row stride
#define MROWS 8192  // BATCH*SEQ
#define C2    0.17677669529663687f  // 1/(sqrt(2)*sqrt(16))

__device__ __forceinline__ u16 f2b(float f) {
  union { float f; unsigned u; } v; v.f = f;
  unsigned u = v.u;
  return (u16)((u + 0x7fffu + ((u >> 16) & 1u)) >> 16);
}
__device__ __forceinline__ float b2f(u16 s) {
  union { unsigned u; float f; } v; v.u = ((unsigned)s) << 16; return v.f;
}

typedef const unsigned int __attribute__((address_space(1)))* gas1;
typedef unsigned int __attribute__((address_space(3)))* las3;
__device__ __forceinline__ void gl_lds16(const u16* g, u16* l) {
  __builtin_amdgcn_global_load_lds((gas1)(const void*)g, (las3)(void*)l, 16, 0, 0);
}

// Fused prep: x->bf16 (blocks 0..8191), 4 weight cast-transposes (8192..10751), bias concat (10752)
__global__ __launch_bounds__(256) void prep(const float* __restrict__ x, u16* __restrict__ xb,
                                            const float* __restrict__ Wq, const float* __restrict__ Wk,
                                            const float* __restrict__ Wv, const float* __restrict__ Wo,
                                            u16* __restrict__ wqkT, u16* __restrict__ wvT, u16* __restrict__ woT,
                                            const float* __restrict__ bq, const float* __restrict__ bk,
                                            float* __restrict__ bqk) {
  __shared__ float tile[32][33];
  int id = blockIdx.x;
  if (id < 8192) {
    int i = id * 256 + threadIdx.x;
    float4 v = ((const float4*)x)[i];
    u16 r[4] = {f2b(v.x), f2b(v.y), f2b(v.z), f2b(v.w)};
    ((uint2*)xb)[i] = *(uint2*)r;
    return;
  }
  id -= 8192;
  if (id < 2560) {
    const float* src; u16* dst; int N, t;
    if (id < 256)       { src = Wq; dst = wqkT;            N = 256;  t = id; }
    else if (id < 512)  { src = Wk; dst = wqkT + 256 * DM; N = 256;  t = id - 256; }
    else if (id < 1536) { src = Wv; dst = wvT;             N = 1024; t = id - 512; }
    else                { src = Wo; dst = woT;             N = 1024; t = id - 1536; }
    int nt = N / 32;
    int n0 = (t % nt) * 32, k0 = (t / nt) * 32;
    int tx = threadIdx.x & 31, ty = threadIdx.x >> 5;
    for (int i = ty; i < 32; i += 8)
      tile[i][tx] = src[(size_t)(k0 + i) * N + n0 + tx];
    __syncthreads();
    for (int i = ty; i < 32; i += 8)
      dst[(size_t)(n0 + i) * DM + k0 + tx] = f2b(tile[tx][i]);
    return;
  }
  int i = threadIdx.x;
  bqk[i] = bq[i];
  bqk[256 + i] = bk[i];
}

// C = A(MxK bf16 rm) @ BT^T + bias.  BT is [N][K] bf16 row-major.
// outF: fp32 rm; outB: bf16 rm; outT: bf16 TRANSPOSED [col*M + row] (packed uint2 stores).
__global__ __launch_bounds__(256) void gemm128(const u16* __restrict__ A, const u16* __restrict__ BT,
                                               const float* __restrict__ bias, int M, int N, int K,
                                               float* __restrict__ outF, u16* __restrict__ outB,
                                               u16* __restrict__ outT) {
  __shared__ __align__(16) u16 As[128 * 32];
  __shared__ __align__(16) u16 Bs[128 * 32];
  const int tid = threadIdx.x;
  const int wave = tid >> 6, lane = tid & 63, qd = lane >> 4, ln = lane & 15;
  const int wr = (wave >> 1) * 64, wc = (wave & 1) * 64;
  const int m0 = blockIdx.y * 128, n0 = blockIdx.x * 128;
  f32x4 acc[4][4];
#pragma unroll
  for (int i = 0; i < 4; i++)
#pragma unroll
    for (int j = 0; j < 4; j++) acc[i][j] = (f32x4){0.f, 0.f, 0.f, 0.f};
  const int sr = tid >> 2, sk = (tid & 3) * 8;
  const u16* gA0 = A + (size_t)(m0 + sr) * K + sk;
  const u16* gA1 = A + (size_t)(m0 + 64 + sr) * K + sk;
  const u16* gB0 = BT + (size_t)(n0 + sr) * K + sk;
  const u16* gB1 = BT + (size_t)(n0 + 64 + sr) * K + sk;
  u16* lA0 = &As[(size_t)(wave * 64) * 8];
  u16* lA1 = &As[(size_t)(256 + wave * 64) * 8];
  u16* lB0 = &Bs[(size_t)(wave * 64) * 8];
  u16* lB1 = &Bs[(size_t)(256 + wave * 64) * 8];
  for (int kk = 0; kk < K; kk += 32) {
    gl_lds16(gA0 + kk, lA0);
    gl_lds16(gA1 + kk, lA1);
    gl_lds16(gB0 + kk, lB0);
    gl_lds16(gB1 + kk, lB1);
    __syncthreads();
    bf16x8 af[4], bf[4];
#pragma unroll
    for (int t = 0; t < 4; t++) {
      af[t] = *(const bf16x8*)&As[(wr + t * 16 + ln) * 32 + qd * 8];
      bf[t] = *(const bf16x8*)&Bs[(wc + t * 16 + ln) * 32 + qd * 8];
    }
#pragma unroll
    for (int mt = 0; mt < 4; mt++)
#pragma unroll
      for (int nt = 0; nt < 4; nt++)
        acc[mt][nt] = __builtin_amdgcn_mfma_f32_16x16x32_bf16(af[mt], bf[nt], acc[mt][nt], 0, 0, 0);
    __syncthreads();
  }
  if (outT) {
#pragma unroll
    for (int nt = 0; nt < 4; nt++) {
      int col = n0 + wc + nt * 16 + ln;
      float bv = bias[col];
#pragma unroll
      for (int mt = 0; mt < 4; mt++) {
        u16 pk[4];
#pragma unroll
        for (int r = 0; r < 4; r++) pk[r] = f2b(acc[mt][nt][r] + bv);
        int row0 = m0 + wr + mt * 16 + qd * 4;
        *(uint2*)&outT[(size_t)col * M + row0] = *(uint2*)pk;
      }
    }
    return;
  }
#pragma unroll
  for (int nt = 0; nt < 4; nt++) {
    int col = n0 + wc + nt * 16 + ln;
    float bv = bias[col];
#pragma unroll
    for (int mt = 0; mt < 4; mt++) {
#pragma unroll
      for (int r = 0; r < 4; r++) {
        int row = m0 + wr + mt * 16 + qd * 4 + r;
        float v = acc[mt][nt][r] + bv;
        if (outF) outF[(size_t)row * N + col] = v;
        else      outB[(size_t)row * N + col] = f2b(v);
      }
    }
  }
}

// Per (b,h,chunk of 128): ckvT[hd][e] = sum_t Kf[t][e]*V[t][hd] (bf16), ck[e] = colsum Kf (fp32)
__global__ __launch_bounds__(256) void chunk_sums(const float* __restrict__ qkw, const u16* __restrict__ vbT,
                                                  u16* __restrict__ ckvT, float* __restrict__ ck) {
  __shared__ float kl[CHK][17];
  __shared__ __align__(16) u16 kfT[4][16][136];  // per-wave [e_local][t]
  const int tid = threadIdx.x;
  const int bh = blockIdx.x / NC, c = blockIdx.x % NC;
  const int b = bh >> 4, h = bh & 15;
  const int wave = tid >> 6, lane = tid & 63, qd = lane >> 4, ln = lane & 15;
  const size_t rowbase = (size_t)(b * SEQ + c * CHK);
#pragma unroll
  for (int it = 0; it < 2; it++) {
    int i = tid + it * 256;
    int tt = i >> 2, f0 = (i & 3) * 4;
    float4 v = *(const float4*)&qkw[(rowbase + tt) * QKS + 256 + h * FEAT + f0];
    kl[tt][f0] = v.x; kl[tt][f0 + 1] = v.y; kl[tt][f0 + 2] = v.z; kl[tt][f0 + 3] = v.w;
  }
  uint4 bVv[4][4];
#pragma unroll
  for (int kk2 = 0; kk2 < 4; kk2++)
#pragma unroll
    for (int nt = 0; nt < 4; nt++)
      bVv[kk2][nt] = *(const uint4*)&vbT[(size_t)(h * HD + nt * 16 + ln) * MROWS +
                                         rowbase + kk2 * 32 + qd * 8];
  __syncthreads();
  const size_t obase = (size_t)(bh * NC + c) * HD;
  for (int mt = wave; mt < 18; mt += 4) {
#pragma unroll
    for (int el = 0; el < 16; el++) {
      int e = mt * 16 + el;
#pragma unroll
      for (int hh = 0; hh < 2; hh++) {
        int t = lane + hh * 64;
        float val;
        if (e == 0) val = 1.0f;
        else if (e < 17) val = 0.5f * kl[t][e - 1];
        else if (e < EXPD) { int u = e - 17; val = C2 * kl[t][u >> 4] * kl[t][u & 15]; }
        else val = 0.0f;
        kfT[wave][el][t] = f2b(val);
      }
    }
    f32x4 acc[4];
#pragma unroll
    for (int nt = 0; nt < 4; nt++) acc[nt] = (f32x4){0.f, 0.f, 0.f, 0.f};
#pragma unroll
    for (int kk2 = 0; kk2 < 4; kk2++) {
      bf16x8 a = *(const bf16x8*)&kfT[wave][ln][kk2 * 32 + qd * 8];
#pragma unroll
      for (int nt = 0; nt < 4; nt++) {
        bf16x8 bb = *(const bf16x8*)&bVv[kk2][nt];
        acc[nt] = __builtin_amdgcn_mfma_f32_16x16x32_bf16(a, bb, acc[nt], 0, 0, 0);
      }
    }
#pragma unroll
    for (int nt = 0; nt < 4; nt++) {
      u16 pk[4];
#pragma unroll
      for (int r = 0; r < 4; r++) pk[r] = f2b(acc[nt][r]);
      *(uint2*)&ckvT[(obase + nt * 16 + ln) * EXPP + mt * 16 + qd * 4] = *(uint2*)pk;
    }
  }
  for (int e = tid; e < EXPP; e += 256) {
    float s = 0.f;
    if (e == 0) s = (float)CHK;
    else if (e < 17) { float t = 0.f; for (int tt = 0; tt < CHK; tt++) t += kl[tt][e - 1]; s = 0.5f * t; }
    else if (e < EXPD) {
      int u = e - 17, i0 = u >> 4, j0 = u & 15; float t = 0.f;
      for (int tt = 0; tt < CHK; tt++) t += kl[tt][i0] * kl[tt][j0];
      s = C2 * t;
    }
    ck[(size_t)(bh * NC + c) * EXPP + e] = s;
  }
}

// Exclusive prefix over chunks (in place, bf16) on ckvT [bh][c][hd][EXPP]; inclusive final -> out_kv.
// Depth-2 prefetch. Blocks with eg==9 do the kst (ck) prefix for this bh.
__global__ __launch_bounds__(256) void kv_prefix(u16* __restrict__ ckvT, const float* __restrict__ kv0,
                                                 float* __restrict__ out_kv,
                                                 float* __restrict__ ck, const float* __restrict__ k0,
                                                 float* __restrict__ out_k) {
  const int tid = threadIdx.x;
  const int bh = blockIdx.x / 10, eg = blockIdx.x % 10;
  if (eg == 9) {
    for (int e = tid; e < EXPP; e += 256) {
      float S = (e < EXPD) ? k0[(size_t)bh * EXPD + e] : 0.f;
      for (int c = 0; c < NC; c++) {
        size_t idx = ((size_t)bh * NC + c) * EXPP + e;
        float v = ck[idx];
        ck[idx] = S;
        S += v;
      }
      if (e < EXPD) out_k[(size_t)bh * EXPD + e] = S;
    }
    return;
  }
  const int hd = tid >> 2;
  const int e0 = eg * 32 + (tid & 3) * 8;
  float S[8];
#pragma unroll
  for (int j = 0; j < 8; j++) {
    int e = e0 + j;
    S[j] = (e < EXPD) ? kv0[((size_t)bh * EXPD + e) * HD + hd] : 0.f;
  }
  u16* base = ckvT + ((size_t)bh * NC * HD + hd) * EXPP + e0;
  const size_t cstride = (size_t)HD * EXPP;
  uint4 v0 = *(const uint4*)base;
  uint4 v1 = *(const uint4*)(base + cstride);
  for (int c = 0; c < NC; c++) {
    uint4 vn = v1;
    if (c + 2 < NC) vn = *(const uint4*)(base + (size_t)(c + 2) * cstride);
    union { uint4 q; u16 s[8]; } pk;
#pragma unroll
    for (int j = 0; j < 8; j++) pk.s[j] = f2b(S[j]);
    *(uint4*)(base + (size_t)c * cstride) = pk.q;
    union { uint4 q; u16 s[8]; } vv; vv.q = v0;
#pragma unroll
    for (int j = 0; j < 8; j++) S[j] += b2f(vv.s[j]);
    v0 = v1; v1 = vn;
  }
#pragma unroll
  for (int j = 0; j < 8; j++) {
    int e = e0 + j;
    if (e < EXPD) out_kv[((size_t)bh * EXPD + e) * HD + hd] = S[j];
  }
}

// Per (b,h,chunk of 128): O = (Qf@S + mask_incl(poly(QK^T))@V) / den.
// Phases: load -> Qf@S (dbuf featurize) -> scores (poly MFMA) -> al -> A@V -> den -> out.
__global__ __launch_bounds__(256) void out_chunk(const float* __restrict__ qkw, const u16* __restrict__ vbT,
                                                 const u16* __restrict__ ckvT, const float* __restrict__ ck,
                                                 u16* __restrict__ ob) {
  __shared__ float ql[CHK][17];
  __shared__ __align__(16) u16 pool[4 * CHK * 40];   // qlb | klb | qfs[0] | qfs[1]; al overlays
  __shared__ float kstl[EXPP];
  __shared__ float denl[CHK];
  u16 (*qlb)[40] = (u16(*)[40])pool;
  u16 (*klb)[40] = (u16(*)[40])(pool + CHK * 40);
  u16 (*qfs)[CHK][40] = (u16(*)[CHK][40])(pool + 2 * CHK * 40);
  u16 (*al)[136] = (u16(*)[136])pool;                // 34816 B <= 40960 B
  const int tid = threadIdx.x;
  const int bh = blockIdx.x / NC, c = blockIdx.x % NC;
  const int b = bh >> 4, h = bh & 15;
  const int wave = tid >> 6, lane = tid & 63, qd = lane >> 4, ln = lane & 15;
  const size_t rowbase = (size_t)(b * SEQ + c * CHK);
#pragma unroll
  for (int it = 0; it < 2; it++) {
    int i = tid + it * 256;
    int tt = i >> 2, f0 = (i & 3) * 4;
    float4 vq = *(const float4*)&qkw[(rowbase + tt) * QKS + h * FEAT + f0];
    float4 vk = *(const float4*)&qkw[(rowbase + tt) * QKS + 256 + h * FEAT + f0];
    ql[tt][f0] = vq.x; ql[tt][f0 + 1] = vq.y; ql[tt][f0 + 2] = vq.z; ql[tt][f0 + 3] = vq.w;
    u16 qb[4] = {f2b(vq.x), f2b(vq.y), f2b(vq.z), f2b(vq.w)};
    u16 kb[4] = {f2b(vk.x), f2b(vk.y), f2b(vk.z), f2b(vk.w)};
    *(uint2*)&qlb[tt][f0] = *(uint2*)qb;
    *(uint2*)&klb[tt][f0] = *(uint2*)kb;
    *(uint2*)&qlb[tt][16 + f0] = (uint2){0u, 0u};
    *(uint2*)&klb[tt][16 + f0] = (uint2){0u, 0u};
  }
  const size_t cbase = (size_t)(bh * NC + c);
  for (int e = tid; e < EXPP; e += 256) kstl[e] = ck[cbase * EXPP + e];
  const u16* sptr = ckvT + (cbase * HD + wave * 16 + ln) * EXPP + qd * 8;
  uint4 bSv[9];
#pragma unroll
  for (int kt = 0; kt < 9; kt++) bSv[kt] = *(const uint4*)(sptr + kt * 32);
  uint4 bVv[4];
#pragma unroll
  for (int kk2 = 0; kk2 < 4; kk2++)
    bVv[kk2] = *(const uint4*)&vbT[(size_t)(h * HD + wave * 16 + ln) * MROWS +
                                   rowbase + kk2 * 32 + qd * 8];
  auto feat = [&](int buf, int kt) {
#pragma unroll
    for (int ii = 0; ii < 16; ii++) {
      int i = tid + ii * 256;
      int tt = i >> 5, el = i & 31;
      int e = kt * 32 + el;
      float qv;
      if (e == 0) qv = 1.f;
      else if (e < 17) qv = 0.5f * ql[tt][e - 1];
      else if (e < EXPD) { int u = e - 17; qv = C2 * ql[tt][u >> 4] * ql[tt][u & 15]; }
      else qv = 0.f;
      qfs[buf][tt][el] = f2b(qv);
    }
  };
  __syncthreads();
  feat(0, 0);
  __syncthreads();
  f32x4 accO[8];
#pragma unroll
  for (int mt = 0; mt < 8; mt++) accO[mt] = (f32x4){0.f, 0.f, 0.f, 0.f};
  for (int kt = 0; kt < 9; kt++) {
    int cur = kt & 1;
    if (kt < 8) feat(cur ^ 1, kt + 1);
    bf16x8 bS = *(const bf16x8*)&bSv[kt];
#pragma unroll
    for (int mt = 0; mt < 8; mt++) {
      bf16x8 a = *(const bf16x8*)&qfs[cur][mt * 16 + ln][qd * 8];
      accO[mt] = __builtin_amdgcn_mfma_f32_16x16x32_bf16(a, bS, accO[mt], 0, 0, 0);
    }
    __syncthreads();
  }
  // scores: u = q.k for s-tiles {wave, wave+4}
  f32x4 accU[8][2];
#pragma unroll
  for (int st2 = 0; st2 < 2; st2++) {
    bf16x8 bU = *(const bf16x8*)&klb[(wave + st2 * 4) * 16 + ln][qd * 8];
#pragma unroll
    for (int mt = 0; mt < 8; mt++) {
      bf16x8 aU = *(const bf16x8*)&qlb[mt * 16 + ln][qd * 8];
      accU[mt][st2] = __builtin_amdgcn_mfma_f32_16x16x32_bf16(aU, bU, (f32x4){0.f, 0.f, 0.f, 0.f}, 0, 0, 0);
    }
  }
  __syncthreads();   // all qlb/klb reads done before al overwrites them
#pragma unroll
  for (int mt = 0; mt < 8; mt++)
#pragma unroll
    for (int st2 = 0; st2 < 2; st2++)
#pragma unroll
      for (int r = 0; r < 4; r++) {
        int t = mt * 16 + qd * 4 + r, s = (wave + st2 * 4) * 16 + ln;
        float u = accU[mt][st2][r];
        float sc = 1.f + 0.25f * u + 0.03125f * u * u;
        al[t][s] = f2b((s <= t) ? sc : 0.f);
      }
  __syncthreads();
#pragma unroll
  for (int kk2 = 0; kk2 < 4; kk2++) {
    bf16x8 bb = *(const bf16x8*)&bVv[kk2];
#pragma unroll
    for (int mt = 0; mt < 8; mt++) {
      bf16x8 a = *(const bf16x8*)&al[mt * 16 + ln][kk2 * 32 + qd * 8];
      accO[mt] = __builtin_amdgcn_mfma_f32_16x16x32_bf16(a, bb, accO[mt], 0, 0, 0);
    }
  }
  {
    int t = tid >> 1, p = tid & 1;
    float q16[16];
#pragma unroll
    for (int j = 0; j < 16; j++) q16[j] = ql[t][j];
    float s = 0.f;
#pragma unroll
    for (int i2 = 0; i2 < 8; i2++) {
      int i = p * 8 + i2;
      float inner = 0.f;
#pragma unroll
      for (int j = 0; j < 16; j++) inner += q16[j] * kstl[17 + i * 16 + j];
      s += q16[i] * inner;
    }
    s *= C2;
    float s1 = 0.f;
#pragma unroll
    for (int j2 = 0; j2 < 8; j2++) { int j = p * 8 + j2; s1 += q16[j] * kstl[1 + j]; }
    s += 0.5f * s1;
    if (p == 0) s += kstl[0] + 1e-6f;
    float da = 0.f;
    for (int s2 = 0; s2 < 64; s2++) da += b2f(al[t][p * 64 + s2]);
    s += da;
    s += __shfl_xor(s, 1);
    if (p == 0) denl[t] = s;
  }
  __syncthreads();
#pragma unroll
  for (int mt = 0; mt < 8; mt++)
#pragma unroll
    for (int r = 0; r < 4; r++) {
      int t = mt * 16 + qd * 4 + r;
      ob[(rowbase + t) * DM + h * HD + wave * 16 + ln] = f2b(accO[mt][r] / denl[t]);
    }
}

extern "C" void kernel_launch(void* const* d_in, const int* in_sizes, int n_in,
                              void* d_out, int out_size, void* d_ws, size_t ws_size,
                              hipStream_t stream) {
  (void)in_sizes; (void)n_in; (void)out_size;
  const float* x   = (const float*)d_in[0];
  const float* kv0 = (const float*)d_in[1];
  const float* k0  = (const float*)d_in[2];
  const float* bq  = (const float*)d_in[4];
  const float* bk  = (const float*)d_in[6];
  const float* bv  = (const float*)d_in[8];
  const float* bo  = (const float*)d_in[10];
  float* out = (float*)d_out;
  char* ws = (char*)d_ws;
  size_t off = 0;
  auto take = [&](size_t bytes) { char* p = ws + off; off += (bytes + 255) & ~(size_t)255; return p; };
  u16*   xb   = (u16*)  take((size_t)BATCH * SEQ * DM * 2);
  u16*   wqkT = (u16*)  take((size_t)QKS * DM * 2);
  u16*   wvT  = (u16*)  take((size_t)DM * DM * 2);
  u16*   woT  = (u16*)  take((size_t)DM * DM * 2);
  float* bqk  = (float*)take((size_t)QKS * 4);
  float* qkw  = (float*)take((size_t)BATCH * SEQ * QKS * 4);
  u16*   vbT  = (u16*)  take((size_t)BATCH * SEQ * DM * 2);
  u16*   ckvT = (u16*)  take((size_t)BH * NC * EXPP * HD * 2);
  float* ck   = (float*)take((size_t)BH * NC * EXPP * 4);
  u16*   ob   = (u16*)  take((size_t)BATCH * SEQ * DM * 2);
  if (off > ws_size) return;

  float* out_kv = out + (size_t)BATCH * SEQ * DM;
  float* out_k  = out_kv + (size_t)BH * EXPD * HD;

  prep<<<8192 + 2560 + 1, 256, 0, stream>>>(x, xb,
      (const float*)d_in[3], (const float*)d_in[5], (const float*)d_in[7], (const float*)d_in[9],
      wqkT, wvT, woT, bq, bk, bqk);

  gemm128<<<dim3(4, 64), 256, 0, stream>>>(xb, wqkT, bqk, MROWS, QKS, DM, qkw, nullptr, nullptr);
  gemm128<<<dim3(8, 64), 256, 0, stream>>>(xb, wvT,  bv,  MROWS, DM,  DM, nullptr, nullptr, vbT);

  chunk_sums<<<BH * NC, 256, 0, stream>>>(qkw, vbT, ckvT, ck);
  kv_prefix<<<BH * 10, 256, 0, stream>>>(ckvT, kv0, out_kv, ck, k0, out_k);
  out_chunk<<<BH * NC, 256, 0, stream>>>(qkw, vbT, ckvT, ck, ob);

  gemm128<<<dim3(8, 64), 256, 0, stream>>>(ob, woT, bo, MROWS, DM, DM, out, nullptr, nullptr);
}